// Round 11
// baseline (250.531 us; speedup 1.0000x reference)
//
#include <hip/hip_runtime.h>

typedef _Float16 half_t;
typedef __attribute__((ext_vector_type(8))) _Float16 f16x8;   // 8 fp16 = 4 VGPRs
typedef __attribute__((ext_vector_type(4))) _Float16 f16x4;
typedef __attribute__((ext_vector_type(4))) float f32x4;
typedef __attribute__((ext_vector_type(4))) float float4v;

__device__ __forceinline__ void gload_lds16(const void* g, void* l) {
  __builtin_amdgcn_global_load_lds(
      (const __attribute__((address_space(1))) void*)g,
      (__attribute__((address_space(3))) void*)l, 16, 0, 0);
}

// ---------------------------------------------------------------------------
// Big-GEMM v3 (8-phase): C[16384][1024] = A * B, Bt = B^T [1024][1024].
// 256x256 tile, 8 waves (2M x 4N, wave tile 128x64). K-tiles of BK=64,
// double-buffered (2 x 64KB). 4 phases per K-tile; per phase:
//   {4xA ds_read (+4xB even phases) | stage 1 K-half (2 gload_lds) |
//    barrier | lgkmcnt(0) | setprio(1) 16 MFMA setprio(0) | vmcnt | barrier}
// Halves split along K (A-Kh0,B-Kh0,A-Kh1,B-Kh1) -> each staged half has
// 3 phases of landing slack; vmcnt(4) at phases 1,3 (never 0 mid-loop).
// ---------------------------------------------------------------------------
template<int OUTF16>
__global__ __launch_bounds__(512, 2)
void gemm_big(const half_t* __restrict__ A, const half_t* __restrict__ Bt,
              void* __restrict__ Cv, const float* __restrict__ bias, float alpha)
{
  // buffer d (64KB at d*65536): A-Kh0 | A-Kh1 | B-Kh0 | B-Kh1 (16KB each)
  // half layout: row r (0..255) * 64B, 4 x 16B slots (slot = swizzled k-window)
  __shared__ __attribute__((aligned(16))) char lds[131072];
  const int tid = threadIdx.x, w = tid >> 6, lane = tid & 63;
  const int wr = w >> 2, wc = w & 3;          // wave grid 2M x 4N
  const int g = lane >> 4, cc = lane & 15;
  const int m0 = blockIdx.x * 256, n0 = blockIdx.y * 256;

  // staging map: thread -> row srow2 (+128 on 2nd call), slot sslot
  const int srow2 = tid >> 2, sslot = tid & 3;
  const int swslot = sslot ^ ((srow2 >> 1) & 3);     // inverse swizzle on source
  // read map: swizzled 16B slot for fragment reads (g = k-slot)
  const int swr = (g ^ ((cc >> 1) & 3)) << 4;

  const f32x4 zero = {0.f, 0.f, 0.f, 0.f};
  f32x4 acc[8][4];
#pragma unroll
  for (int i = 0; i < 8; ++i)
#pragma unroll
    for (int j = 0; j < 4; ++j) acc[i][j] = zero;

  // stage one K-half (16KB) of K-tile `ktile` into buffer `sb`
  // hh: 0=A-Kh0, 1=B-Kh0, 2=A-Kh1, 3=B-Kh1
  auto STAGE_HALF = [&](int ktile, int hh, char* sb) {
    const int kk = hh >> 1, isB = hh & 1;
    const half_t* src = isB ? Bt : A;
    const int base_row = isB ? n0 : m0;
    const long rowoff = (long)(base_row + srow2) * 1024 + ktile * 64 + kk * 32 + swslot * 8;
    char* d = sb + isB * 32768 + kk * 16384;
    gload_lds16(src + rowoff,          d + tid * 16);          // rows 0..127
    gload_lds16(src + rowoff + 131072, d + 8192 + tid * 16);   // rows 128..255
  };

  // prologue: stage K-tile 0 (4 halves, in order), wait first 2 halves
  {
    char* b0 = lds;
    STAGE_HALF(0, 0, b0); STAGE_HALF(0, 1, b0);
    STAGE_HALF(0, 2, b0); STAGE_HALF(0, 3, b0);
  }
  asm volatile("s_waitcnt vmcnt(4)" ::: "memory");   // A-Kh0,B-Kh0 landed
  __builtin_amdgcn_s_barrier();

#pragma unroll 1
  for (int n = 0; n < 16; ++n) {
    const char* rb = lds + ((n & 1) << 16);        // read: K-tile n
    char* sb = lds + (((n + 1) & 1) << 16);        // stage: K-tile n+1
    f16x8 bf[4];
#pragma unroll
    for (int ph = 0; ph < 4; ++ph) {
      const int kk = ph >> 1, fh = ph & 1;
      // --- ds reads (this phase's fragments) ---
      f16x8 af[4];
      const char* Ah = rb + kk * 16384;
#pragma unroll
      for (int mf = 0; mf < 4; ++mf)
        af[mf] = *(const f16x8*)(Ah + (wr * 128 + fh * 64 + mf * 16 + cc) * 64 + swr);
      if (fh == 0) {
        const char* Bh = rb + 32768 + kk * 16384;
#pragma unroll
        for (int nf = 0; nf < 4; ++nf)
          bf[nf] = *(const f16x8*)(Bh + (wc * 64 + nf * 16 + cc) * 64 + swr);
      }
      // --- stage 1 K-half of next K-tile ---
      if (n < 15) STAGE_HALF(n + 1, ph, sb);
      __builtin_amdgcn_sched_barrier(0);
      __builtin_amdgcn_s_barrier();
      asm volatile("s_waitcnt lgkmcnt(0)" ::: "memory");
      __builtin_amdgcn_sched_barrier(0);
      // --- MFMA cluster (16) ---
      __builtin_amdgcn_s_setprio(1);
#pragma unroll
      for (int mf = 0; mf < 4; ++mf)
#pragma unroll
        for (int nf = 0; nf < 4; ++nf)
          acc[fh * 4 + mf][nf] =
              __builtin_amdgcn_mfma_f32_16x16x32_f16(af[mf], bf[nf], acc[fh * 4 + mf][nf], 0, 0, 0);
      __builtin_amdgcn_s_setprio(0);
      __builtin_amdgcn_sched_barrier(0);
      // --- counted vmcnt at phases 1 and 3 ---
      if (ph == 1) {
        if (n < 15) { asm volatile("s_waitcnt vmcnt(4)" ::: "memory"); }
        else        { asm volatile("s_waitcnt vmcnt(0)" ::: "memory"); }
      } else if (ph == 3) {
        if (n < 15) { asm volatile("s_waitcnt vmcnt(4)" ::: "memory"); }
      }
      __builtin_amdgcn_s_barrier();
    }
  }

#pragma unroll
  for (int mf = 0; mf < 8; ++mf)
#pragma unroll
    for (int nf = 0; nf < 4; ++nf)
#pragma unroll
      for (int r = 0; r < 4; ++r) {
        const int row = m0 + wr * 128 + mf * 16 + g * 4 + r;  // D: row=(l>>4)*4+reg
        const int col = n0 + wc * 64 + nf * 16 + cc;          //    col=l&15
        float v = (acc[mf][nf][r] + bias[col]) * alpha;
        if (OUTF16) ((half_t*)Cv)[(long)row * 1024 + col] = (half_t)v;
        else        ((float*)Cv)[(long)row * 1024 + col] = v;
      }
}

// ---------------------------------------------------------------------------
// General tiled GEMM (128x128, m97-structure) for the small/odd shapes.
// MODE 0: C = acc ; MODE 1: C = (acc + bias[col]) * alpha
// MODE 2: C = acc + rowscale[row] * bias[col]
// MODE 3: split-K partials, plain f32 stores to slice ks
// MODE 4: MODE2 value, stored head-blocked: [col/64][row][col&63] (fp16)
// ---------------------------------------------------------------------------
template<int BM, int BN, int WM, int WN, int OUTF16, int MODE, int SK>
__global__ __launch_bounds__(256, 2)
void gemm_bt(const half_t* __restrict__ A, const half_t* __restrict__ Bt,
             void* __restrict__ Cv, const float* __restrict__ bias,
             const float* __restrict__ rowscale,
             int M, int N, int K, int lda, int ldb, int ldc, float alpha,
             long sA, long sB, long sC)
{
  constexpr int FM = WM / 16, FN = WN / 16, CW = BN / WN;
  __shared__ __attribute__((aligned(16))) half_t As[BM * 32];
  __shared__ __attribute__((aligned(16))) half_t Bs[BN * 32];

  const int tid = threadIdx.x, w = tid >> 6, lane = tid & 63;
  const int wr = w / CW, wc = w % CW;
  const int z = blockIdx.z / SK, ks = blockIdx.z % SK;
  const half_t* Ab = A + (long)z * sA;
  const half_t* Bb = Bt + (long)z * sB;
  const int m0 = blockIdx.x * BM, n0 = blockIdx.y * BN;
  const int g = lane >> 4, cc = lane & 15;
  const int srow = lane >> 2, scol = (lane & 3) * 8;   // staging lane map

  const f32x4 zero = {0.f, 0.f, 0.f, 0.f};
  f32x4 acc[FM][FN];
#pragma unroll
  for (int i = 0; i < FM; ++i)
#pragma unroll
    for (int j = 0; j < FN; ++j) acc[i][j] = zero;

  const int kchunk = K / SK;
  for (int kt = ks * kchunk; kt < (ks + 1) * kchunk; kt += 32) {
#pragma unroll
    for (int j = 0; j < BM / 64; ++j) {
      const int bi = w * (BM / 64) + j;
      gload_lds16(Ab + (long)(m0 + bi * 16 + srow) * lda + kt + scol, &As[bi * 512]);
    }
#pragma unroll
    for (int j = 0; j < BN / 64; ++j) {
      const int bi = w * (BN / 64) + j;
      gload_lds16(Bb + (long)(n0 + bi * 16 + srow) * ldb + kt + scol, &Bs[bi * 512]);
    }
    __syncthreads();   // drains vmcnt -> staged data visible

    f16x8 af[FM], bf[FN];
#pragma unroll
    for (int i = 0; i < FM; ++i)
      af[i] = *(const f16x8*)&As[(wr * WM + i * 16 + cc) * 32 + g * 8];
#pragma unroll
    for (int j = 0; j < FN; ++j)
      bf[j] = *(const f16x8*)&Bs[(wc * WN + j * 16 + cc) * 32 + g * 8];
#pragma unroll
    for (int i = 0; i < FM; ++i)
#pragma unroll
      for (int j = 0; j < FN; ++j)
        acc[i][j] = __builtin_amdgcn_mfma_f32_16x16x32_f16(af[i], bf[j], acc[i][j], 0, 0, 0);
    __syncthreads();   // before next-tile staging overwrites LDS
  }

  const long coff = (long)z * sC;
#pragma unroll
  for (int i = 0; i < FM; ++i)
#pragma unroll
    for (int j = 0; j < FN; ++j)
#pragma unroll
      for (int r = 0; r < 4; ++r) {
        const int row = m0 + wr * WM + i * 16 + g * 4 + r;   // C/D: row=(l>>4)*4+reg
        const int col = n0 + wc * WN + j * 16 + cc;          //      col=l&15
        float v = acc[i][j][r];
        if (MODE == 1) v = (v + bias[col]) * alpha;
        if (MODE == 2 || MODE == 4) v = v + rowscale[row] * bias[col];
        if (MODE == 3) {
          const int nb = gridDim.z / SK;   // batches
          ((float*)Cv)[((long)ks * nb + z) * sC + (long)row * ldc + col] = v;
        } else if (MODE == 4) {
          ((half_t*)Cv)[coff + (long)(col >> 6) * ((long)M * 64) + (long)row * 64 + (col & 63)]
              = (half_t)v;
        } else {
          if (OUTF16) ((half_t*)Cv)[coff + (long)row * ldc + col] = (half_t)v;
          else        ((float*)Cv)[coff + (long)row * ldc + col] = v;
        }
      }
}

// ---------------------------------------------------------------------------
// Fused attention v4: LDS-staged K/V per (b,h) block (swizzled, coalesced
// global_load_lds), flash-chunked swapped QK^T -> online softmax -> PV.
// ---------------------------------------------------------------------------
__global__ __launch_bounds__(512, 2)
void attn_fused(const half_t* __restrict__ q, const half_t* __restrict__ kEh,
                const half_t* __restrict__ vFt, half_t* __restrict__ outp, int L)
{
  __shared__ __attribute__((aligned(16))) half_t Ks[256 * 64];  // 32KB
  __shared__ __attribute__((aligned(16))) half_t Vs[64 * 256];  // 32KB
  const int tid = threadIdx.x, w = tid >> 6, lane = tid & 63;
  const int g = lane >> 4, c = lane & 15;
  const int l0 = blockIdx.x * 256, h = blockIdx.y, b = blockIdx.z;

  const half_t* keh = kEh + (long)(b * 16 + h) * 16384;   // [256][64]
  const half_t* vfh = vFt + (long)b * 262144 + (long)h * 16384;  // [64][256]
  const half_t* qb  = q + ((long)b * L + l0 + w * 32) * 1024 + h * 64;
  half_t* ob = outp + ((long)b * L + l0 + w * 32) * 1024 + h * 64;

  // stage kE: linear LDS dest, inverse-swizzled source (16B slots, xor row&7)
#pragma unroll
  for (int i = 0; i < 4; ++i) {
    const int row = i * 64 + (tid >> 3), slot = tid & 7;
    gload_lds16(keh + row * 64 + ((slot ^ (row & 7)) << 3),
                (char*)Ks + i * 8192 + tid * 16);
  }
  // stage vFt: rows of 512B = 32 slots of 16B, same xor on low 3 slot bits
#pragma unroll
  for (int i = 0; i < 4; ++i) {
    const int row = i * 16 + (tid >> 5), slot = tid & 31;
    gload_lds16(vfh + row * 256 + ((slot ^ (row & 7)) << 3),
                (char*)Vs + i * 8192 + tid * 16);
  }

  // q as B-operand fragments (n = qrow_local = fi*16 + c, k = d) — global read
  f16x8 qf[2][2];
#pragma unroll
  for (int fi = 0; fi < 2; ++fi)
#pragma unroll
    for (int ks = 0; ks < 2; ++ks)
      qf[fi][ks] = *(const f16x8*)(qb + (long)(fi * 16 + c) * 1024 + ks * 32 + g * 8);

  __syncthreads();   // staged K/V visible

  const f32x4 zero = {0.f, 0.f, 0.f, 0.f};
  f32x4 o[2][4];
#pragma unroll
  for (int fi = 0; fi < 2; ++fi)
#pragma unroll
    for (int fd = 0; fd < 4; ++fd) o[fi][fd] = zero;
  float mrun[2] = {-3.0e38f, -3.0e38f};
  float lrun[2] = {0.f, 0.f};

  for (int ch = 0; ch < 4; ++ch) {
    // --- QK^T chunk from LDS: S^T = kE · q^T, keys = ch*64 + fj*16 + g*4 + r
    f32x4 s[2][4];
#pragma unroll
    for (int fi = 0; fi < 2; ++fi)
#pragma unroll
      for (int fj = 0; fj < 4; ++fj) s[fi][fj] = zero;
#pragma unroll
    for (int fj = 0; fj < 4; ++fj) {
      const int krow = ch * 64 + fj * 16 + c;
      const char* kb = (const char*)Ks + krow * 128;
      f16x8 k0 = *(const f16x8*)(kb + ((g ^ (c & 7)) << 4));
      f16x8 k1 = *(const f16x8*)(kb + (((4 + g) ^ (c & 7)) << 4));
#pragma unroll
      for (int fi = 0; fi < 2; ++fi) {
        s[fi][fj] = __builtin_amdgcn_mfma_f32_16x16x32_f16(k0, qf[fi][0], s[fi][fj], 0, 0, 0);
        s[fi][fj] = __builtin_amdgcn_mfma_f32_16x16x32_f16(k1, qf[fi][1], s[fi][fj], 0, 0, 0);
      }
    }

    // --- online softmax update (per fi; qrow = col c; reduce across g) ---
    f16x4 p[2][4];
#pragma unroll
    for (int fi = 0; fi < 2; ++fi) {
      float cm = -3.0e38f;
#pragma unroll
      for (int fj = 0; fj < 4; ++fj)
#pragma unroll
        for (int r = 0; r < 4; ++r) cm = fmaxf(cm, s[fi][fj][r]);
      cm = fmaxf(cm, __shfl_xor(cm, 16));
      cm = fmaxf(cm, __shfl_xor(cm, 32));
      const float mnew = fmaxf(mrun[fi], cm);
      const float sc = __expf(mrun[fi] - mnew);   // 0 on first chunk
      float csum = 0.f;
#pragma unroll
      for (int fj = 0; fj < 4; ++fj) {
        f16x4 fr;
#pragma unroll
        for (int r = 0; r < 4; ++r) {
          float e = __expf(s[fi][fj][r] - mnew);
          fr[r] = (half_t)e; csum += e;
        }
        p[fi][fj] = fr;
      }
      csum += __shfl_xor(csum, 16);
      csum += __shfl_xor(csum, 32);
      lrun[fi] = lrun[fi] * sc + csum;
      mrun[fi] = mnew;
#pragma unroll
      for (int fd = 0; fd < 4; ++fd)
#pragma unroll
        for (int r = 0; r < 4; ++r) o[fi][fd][r] *= sc;
    }

    // --- PV chunk from LDS: OUT^T += vFt · P^T (K=16 per mfma) ---
#pragma unroll
    for (int kc = 0; kc < 4; ++kc) {
      const int s16 = ch * 8 + kc * 2 + (g >> 1);
      f16x4 va[4];
#pragma unroll
      for (int fd = 0; fd < 4; ++fd) {
        const int drow = fd * 16 + c;
        va[fd] = *(const f16x4*)((const char*)Vs + drow * 512 +
                                 ((s16 ^ (c & 7)) << 4) + (g & 1) * 8);
      }
#pragma unroll
      for (int fi = 0; fi < 2; ++fi)
#pragma unroll
        for (int fd = 0; fd < 4; ++fd)
          o[fi][fd] = __builtin_amdgcn_mfma_f32_16x16x16f16(va[fd], p[fi][kc], o[fi][fd], 0, 0, 0);
    }
  }

  // store OUT^T * 1/l: row = d = fd*16 + g*4 + r (contiguous -> 8B), col = qrow
#pragma unroll
  for (int fi = 0; fi < 2; ++fi) {
    const float inv = 1.0f / lrun[fi];
#pragma unroll
    for (int fd = 0; fd < 4; ++fd) {
      f16x4 st;
#pragma unroll
      for (int r = 0; r < 4; ++r) st[r] = (half_t)(o[fi][fd][r] * inv);
      *(f16x4*)(ob + (long)(fi * 16 + c) * 1024 + fd * 16 + g * 4) = st;
    }
  }
}

// ---------------------------------------------------------------------------
// helpers
// ---------------------------------------------------------------------------
// sum 4 split-K f32 partial slices [4][4][512][1024] -> fp16 [4][512][1024]
__global__ void reduce4_f16(const float* __restrict__ in, half_t* __restrict__ out) {
  long i = ((long)blockIdx.x * 256 + threadIdx.x) * 4;   // over 2,097,152 elems
  float4v a = *(const float4v*)(in + i);
#pragma unroll
  for (int ks = 1; ks < 4; ++ks) {
    float4v t = *(const float4v*)(in + (long)ks * 2097152 + i);
    a.x += t.x; a.y += t.y; a.z += t.z; a.w += t.w;
  }
  f16x4 o;
  o[0] = (half_t)a.x; o[1] = (half_t)a.y; o[2] = (half_t)a.z; o[3] = (half_t)a.w;
  *(f16x4*)(out + i) = o;
}

// x [4][4096][1024] f32 -> xhf fp16 (same layout) AND xT [4][1024][4096] fp16
__global__ void xpass(const float* __restrict__ x, half_t* __restrict__ xhf,
                      half_t* __restrict__ xT) {
  __shared__ float t[32][33];
  const int b = blockIdx.z, d0 = blockIdx.x * 32, l0 = blockIdx.y * 32;
  const int tx = threadIdx.x, ty = threadIdx.y;
  const float* ip = x + ((long)b * 4096 + l0) * 1024 + d0;
  half_t* oh = xhf + ((long)b * 4096 + l0) * 1024 + d0;
#pragma unroll
  for (int j = 0; j < 4; ++j) {
    float v = ip[(long)(ty + 8 * j) * 1024 + tx];
    t[ty + 8 * j][tx] = v;
    oh[(long)(ty + 8 * j) * 1024 + tx] = (half_t)v;
  }
  __syncthreads();
  half_t* ot = xT + ((long)b * 1024 + d0) * 4096 + l0;
#pragma unroll
  for (int j = 0; j < 4; ++j)
    ot[(long)(ty + 8 * j) * 4096 + tx] = (half_t)t[tx][ty + 8 * j];
}

// E [4096][256] f32 -> E^T [256][4096] fp16, plus colsum(E) -> ssum[256]
__global__ void efpass(const float* __restrict__ in, half_t* __restrict__ outT,
                       float* __restrict__ ssum) {
  __shared__ float t[32][33];
  __shared__ float ps[8][32];
  const int k0 = blockIdx.x * 32, l0 = blockIdx.y * 32;
  const int tx = threadIdx.x, ty = threadIdx.y;
  float p = 0.f;
#pragma unroll
  for (int j = 0; j < 4; ++j) {
    float v = in[(long)(l0 + ty + 8 * j) * 256 + k0 + tx];
    t[ty + 8 * j][tx] = v; p += v;
  }
  ps[ty][tx] = p;
  __syncthreads();
  if (ty == 0) {
    float a = 0.f;
#pragma unroll
    for (int r = 0; r < 8; ++r) a += ps[r][tx];
    atomicAdd(&ssum[k0 + tx], a);
  }
#pragma unroll
  for (int j = 0; j < 4; ++j)
    outT[(long)(k0 + ty + 8 * j) * 4096 + l0 + tx] = (half_t)t[tx][ty + 8 * j];
}

__global__ void transpose_f32_f16(const float* __restrict__ in, half_t* __restrict__ out,
                                  int R, int C) {
  __shared__ float t[32][33];
  const int cx = blockIdx.x * 32 + threadIdx.x;
  const int r0 = blockIdx.y * 32;
#pragma unroll
  for (int j = 0; j < 4; ++j)
    t[threadIdx.y + 8 * j][threadIdx.x] = in[(long)(r0 + threadIdx.y + 8 * j) * C + cx];
  __syncthreads();
  const int rx = r0 + threadIdx.x;
  const int cy = blockIdx.x * 32 + threadIdx.y;
#pragma unroll
  for (int j = 0; j < 4; ++j)
    out[(long)(cy + 8 * j) * R + rx] = (half_t)t[threadIdx.x][threadIdx.y + 8 * j];
}

// ---------------------------------------------------------------------------
extern "C" void kernel_launch(void* const* d_in, const int* in_sizes, int n_in,
                              void* d_out, int out_size, void* d_ws, size_t ws_size,
                              hipStream_t stream)
{
  const float* x  = (const float*)d_in[0];
  const float* Wq = (const float*)d_in[1];
  const float* bq = (const float*)d_in[2];
  const float* Wk = (const float*)d_in[3];
  const float* bk = (const float*)d_in[4];
  const float* Wv = (const float*)d_in[5];
  const float* bv = (const float*)d_in[6];
  const float* E  = (const float*)d_in[7];
  const float* F  = (const float*)d_in[8];
  const float* Wo = (const float*)d_in[9];
  const float* bo = (const float*)d_in[10];
  float* out = (float*)d_out;

  char* ws = (char*)d_ws;
  half_t* xhf  = (half_t*)(ws);                 // 33.5MB; later reused as out_pre
  half_t* xT   = (half_t*)(ws + 33554432);      // 33.5MB (dead after xEF gemm)
  half_t* qhf  = (half_t*)(ws + 67108864);      // 33.5MB
  half_t* Wqt  = (half_t*)(ws + 100663296);
  half_t* Wkt  = Wqt + 1048576;
  half_t* Wvt  = Wkt + 1048576;
  half_t* Wot  = Wvt + 1048576;
  half_t* EFt  = (half_t*)(ws + 109051904);     // [512][4096]: E^T on top of F^T
  half_t* xEF  = (half_t*)(ws + 113246208);     // per b: [512][1024] = [xE; xF]
  half_t* kEb  = (half_t*)(ws + 117440512);     // per b: [16][256][64] head-blocked
  half_t* vFtb = (half_t*)(ws + 119537664);     // per b: [1024][256] (= [16][64][256])
  float*  sEF  = (float*)(ws + 121634816);      // sE[256], sF[256]
  half_t* outp = xhf;                           // out_pre overlays x_f16
  float*  xEFf = (float*)d_out;                 // 33.5MB split-K partials [4][4][512][1024]
                                                // in d_out (overwritten by final GEMM)

  hipMemsetAsync(sEF, 0, 2048, stream);
  dim3 tb(32, 8);
  xpass<<<dim3(32, 128, 4), tb, 0, stream>>>(x, xhf, xT);
  efpass<<<dim3(8, 128, 1), tb, 0, stream>>>(E, EFt, sEF);
  efpass<<<dim3(8, 128, 1), tb, 0, stream>>>(F, EFt + 1048576, sEF + 256);
  transpose_f32_f16<<<dim3(32, 32, 1), tb, 0, stream>>>(Wq, Wqt, 1024, 1024);
  transpose_f32_f16<<<dim3(32, 32, 1), tb, 0, stream>>>(Wk, Wkt, 1024, 1024);
  transpose_f32_f16<<<dim3(32, 32, 1), tb, 0, stream>>>(Wv, Wvt, 1024, 1024);
  transpose_f32_f16<<<dim3(32, 32, 1), tb, 0, stream>>>(Wo, Wot, 1024, 1024);

  // xEF partials: [E^T; F^T] @ x_b  (M=512, N=1024, K=4096) split-K=4, plain f32
  gemm_bt<128,128,64,64,0,3,4><<<dim3(4, 8, 16), 256, 0, stream>>>(
      EFt, xT, (void*)xEFf, nullptr, nullptr, 512, 1024, 4096, 4096, 4096, 1024, 1.f,
      0, 4194304, 524288);
  reduce4_f16<<<2048, 256, 0, stream>>>(xEFf, xEF);

  // q = (x@Wq + bq) * hd^-0.5  -> fp16 [16384][1024]  (8-phase big-GEMM)
  gemm_big<1><<<dim3(64, 4), 512, 0, stream>>>(xhf, Wqt, qhf, bq, 0.125f);
  // kE[b] = xE_b @ Wk + sE*bk  -> head-blocked [b][16][256][64]  (MODE 4)
  gemm_bt<128,128,64,64,1,4,1><<<dim3(2, 8, 4), 256, 0, stream>>>(
      xEF, Wkt, kEb, bk, sEF, 256, 1024, 1024, 1024, 1024, 1024, 1.f,
      524288, 0, 262144);
  // vFt[b] = Wv^T @ xF_b^T + bv*sF  (M=1024, N=256, K=1024) -> [b][16][64][256]
  gemm_bt<128,128,64,64,1,2,1><<<dim3(8, 2, 4), 256, 0, stream>>>(
      Wvt, xEF + 262144, vFtb, sEF + 256, bv, 1024, 256, 1024, 1024, 1024, 256, 1.f,
      0, 524288, 262144);
  // fused qk^T -> softmax -> PV   (writes out_pre fp16 [b][l][h*64+d])
  attn_fused<<<dim3(16, 16, 4), 512, 0, stream>>>(qhf, kEb, vFtb, outp, 4096);
  // out = out_pre @ Wo + bo  (fp32, 8-phase big-GEMM)
  gemm_big<0><<<dim3(64, 4), 512, 0, stream>>>(outp, Wot, (void*)out, bo, 1.0f);
  (void)in_sizes; (void)n_in; (void)out_size; (void)ws_size;
}

// Round 12
// 226.473 us; speedup vs baseline: 1.1062x; 1.1062x over previous
//
#include <hip/hip_runtime.h>

typedef _Float16 half_t;
typedef __attribute__((ext_vector_type(8))) _Float16 f16x8;   // 8 fp16 = 4 VGPRs
typedef __attribute__((ext_vector_type(4))) _Float16 f16x4;
typedef __attribute__((ext_vector_type(4))) float f32x4;
typedef __attribute__((ext_vector_type(4))) float float4v;

__device__ __forceinline__ void gload_lds16(const void* g, void* l) {
  __builtin_amdgcn_global_load_lds(
      (const __attribute__((address_space(1))) void*)g,
      (__attribute__((address_space(3))) void*)l, 16, 0, 0);
}

// ---------------------------------------------------------------------------
// Big-GEMM (8-phase): C[16384][1024] = A * B, Bt = B^T [1024][1024].
// OUTMODE 0: f32 standard, (acc+bias)*alpha
// OUTMODE 1: f16 standard, (acc+bias)*alpha
// OUTMODE 2: f16 head-blocked [b][h][l][d], (acc+bias)*alpha  (q-proj)
// ---------------------------------------------------------------------------
template<int OUTMODE>
__global__ __launch_bounds__(512, 2)
void gemm_big(const half_t* __restrict__ A, const half_t* __restrict__ Bt,
              void* __restrict__ Cv, const float* __restrict__ bias, float alpha)
{
  __shared__ __attribute__((aligned(16))) char lds[131072];
  const int tid = threadIdx.x, w = tid >> 6, lane = tid & 63;
  const int wr = w >> 2, wc = w & 3;          // wave grid 2M x 4N
  const int g = lane >> 4, cc = lane & 15;
  const int m0 = blockIdx.x * 256, n0 = blockIdx.y * 256;

  const int srow2 = tid >> 2, sslot = tid & 3;
  const int swslot = sslot ^ ((srow2 >> 1) & 3);     // inverse swizzle on source
  const int swr = (g ^ ((cc >> 1) & 3)) << 4;        // swizzled read slot

  const f32x4 zero = {0.f, 0.f, 0.f, 0.f};
  f32x4 acc[8][4];
#pragma unroll
  for (int i = 0; i < 8; ++i)
#pragma unroll
    for (int j = 0; j < 4; ++j) acc[i][j] = zero;

  auto STAGE_HALF = [&](int ktile, int hh, char* sb) {
    const int kk = hh >> 1, isB = hh & 1;
    const half_t* src = isB ? Bt : A;
    const int base_row = isB ? n0 : m0;
    const long rowoff = (long)(base_row + srow2) * 1024 + ktile * 64 + kk * 32 + swslot * 8;
    char* d = sb + isB * 32768 + kk * 16384;
    gload_lds16(src + rowoff,          d + tid * 16);
    gload_lds16(src + rowoff + 131072, d + 8192 + tid * 16);
  };

  {
    char* b0 = lds;
    STAGE_HALF(0, 0, b0); STAGE_HALF(0, 1, b0);
    STAGE_HALF(0, 2, b0); STAGE_HALF(0, 3, b0);
  }
  asm volatile("s_waitcnt vmcnt(4)" ::: "memory");
  __builtin_amdgcn_s_barrier();

#pragma unroll 1
  for (int n = 0; n < 16; ++n) {
    const char* rb = lds + ((n & 1) << 16);
    char* sb = lds + (((n + 1) & 1) << 16);
    f16x8 bf[4];
#pragma unroll
    for (int ph = 0; ph < 4; ++ph) {
      const int kk = ph >> 1, fh = ph & 1;
      f16x8 af[4];
      const char* Ah = rb + kk * 16384;
#pragma unroll
      for (int mf = 0; mf < 4; ++mf)
        af[mf] = *(const f16x8*)(Ah + (wr * 128 + fh * 64 + mf * 16 + cc) * 64 + swr);
      if (fh == 0) {
        const char* Bh = rb + 32768 + kk * 16384;
#pragma unroll
        for (int nf = 0; nf < 4; ++nf)
          bf[nf] = *(const f16x8*)(Bh + (wc * 64 + nf * 16 + cc) * 64 + swr);
      }
      if (n < 15) STAGE_HALF(n + 1, ph, sb);
      __builtin_amdgcn_sched_barrier(0);
      __builtin_amdgcn_s_barrier();
      asm volatile("s_waitcnt lgkmcnt(0)" ::: "memory");
      __builtin_amdgcn_sched_barrier(0);
      __builtin_amdgcn_s_setprio(1);
#pragma unroll
      for (int mf = 0; mf < 4; ++mf)
#pragma unroll
        for (int nf = 0; nf < 4; ++nf)
          acc[fh * 4 + mf][nf] =
              __builtin_amdgcn_mfma_f32_16x16x32_f16(af[mf], bf[nf], acc[fh * 4 + mf][nf], 0, 0, 0);
      __builtin_amdgcn_s_setprio(0);
      __builtin_amdgcn_sched_barrier(0);
      if (ph == 1) {
        if (n < 15) { asm volatile("s_waitcnt vmcnt(4)" ::: "memory"); }
        else        { asm volatile("s_waitcnt vmcnt(0)" ::: "memory"); }
      } else if (ph == 3) {
        if (n < 15) { asm volatile("s_waitcnt vmcnt(4)" ::: "memory"); }
      }
      __builtin_amdgcn_s_barrier();
    }
  }

#pragma unroll
  for (int mf = 0; mf < 8; ++mf)
#pragma unroll
    for (int nf = 0; nf < 4; ++nf)
#pragma unroll
      for (int r = 0; r < 4; ++r) {
        const int row = m0 + wr * 128 + mf * 16 + g * 4 + r;  // D: row=(l>>4)*4+reg
        const int col = n0 + wc * 64 + nf * 16 + cc;          //    col=l&15
        float v = (acc[mf][nf][r] + bias[col]) * alpha;
        if (OUTMODE == 0) {
          ((float*)Cv)[(long)row * 1024 + col] = v;
        } else if (OUTMODE == 1) {
          ((half_t*)Cv)[(long)row * 1024 + col] = (half_t)v;
        } else {
          const int bb = row >> 12, l = row & 4095, h = col >> 6, d = col & 63;
          ((half_t*)Cv)[(((long)(bb * 16 + h) * 4096 + l) << 6) + d] = (half_t)v;
        }
      }
}

// ---------------------------------------------------------------------------
// General tiled GEMM for small/odd shapes.
// MODE 0: C = acc ; MODE 1: (acc + bias[col]) * alpha
// MODE 2: acc + rowscale[row] * bias[col]
// MODE 3: split-K partials, plain f32 stores to slice ks
// MODE 4: MODE2 value, stored head-blocked: [col/64][row][col&63] (fp16)
// ---------------------------------------------------------------------------
template<int BM, int BN, int WM, int WN, int OUTF16, int MODE, int SK>
__global__ __launch_bounds__(256, 2)
void gemm_bt(const half_t* __restrict__ A, const half_t* __restrict__ Bt,
             void* __restrict__ Cv, const float* __restrict__ bias,
             const float* __restrict__ rowscale,
             int M, int N, int K, int lda, int ldb, int ldc, float alpha,
             long sA, long sB, long sC)
{
  constexpr int FM = WM / 16, FN = WN / 16, CW = BN / WN;
  __shared__ __attribute__((aligned(16))) half_t As[BM * 32];
  __shared__ __attribute__((aligned(16))) half_t Bs[BN * 32];

  const int tid = threadIdx.x, w = tid >> 6, lane = tid & 63;
  const int wr = w / CW, wc = w % CW;
  const int z = blockIdx.z / SK, ks = blockIdx.z % SK;
  const half_t* Ab = A + (long)z * sA;
  const half_t* Bb = Bt + (long)z * sB;
  const int m0 = blockIdx.x * BM, n0 = blockIdx.y * BN;
  const int g = lane >> 4, cc = lane & 15;
  const int srow = lane >> 2, scol = (lane & 3) * 8;

  const f32x4 zero = {0.f, 0.f, 0.f, 0.f};
  f32x4 acc[FM][FN];
#pragma unroll
  for (int i = 0; i < FM; ++i)
#pragma unroll
    for (int j = 0; j < FN; ++j) acc[i][j] = zero;

  const int kchunk = K / SK;
  for (int kt = ks * kchunk; kt < (ks + 1) * kchunk; kt += 32) {
#pragma unroll
    for (int j = 0; j < BM / 64; ++j) {
      const int bi = w * (BM / 64) + j;
      gload_lds16(Ab + (long)(m0 + bi * 16 + srow) * lda + kt + scol, &As[bi * 512]);
    }
#pragma unroll
    for (int j = 0; j < BN / 64; ++j) {
      const int bi = w * (BN / 64) + j;
      gload_lds16(Bb + (long)(n0 + bi * 16 + srow) * ldb + kt + scol, &Bs[bi * 512]);
    }
    __syncthreads();

    f16x8 af[FM], bf[FN];
#pragma unroll
    for (int i = 0; i < FM; ++i)
      af[i] = *(const f16x8*)&As[(wr * WM + i * 16 + cc) * 32 + g * 8];
#pragma unroll
    for (int j = 0; j < FN; ++j)
      bf[j] = *(const f16x8*)&Bs[(wc * WN + j * 16 + cc) * 32 + g * 8];
#pragma unroll
    for (int i = 0; i < FM; ++i)
#pragma unroll
      for (int j = 0; j < FN; ++j)
        acc[i][j] = __builtin_amdgcn_mfma_f32_16x16x32_f16(af[i], bf[j], acc[i][j], 0, 0, 0);
    __syncthreads();
  }

  const long coff = (long)z * sC;
#pragma unroll
  for (int i = 0; i < FM; ++i)
#pragma unroll
    for (int j = 0; j < FN; ++j)
#pragma unroll
      for (int r = 0; r < 4; ++r) {
        const int row = m0 + wr * WM + i * 16 + g * 4 + r;
        const int col = n0 + wc * WN + j * 16 + cc;
        float v = acc[i][j][r];
        if (MODE == 1) v = (v + bias[col]) * alpha;
        if (MODE == 2 || MODE == 4) v = v + rowscale[row] * bias[col];
        if (MODE == 3) {
          const int nb = gridDim.z / SK;
          ((float*)Cv)[((long)ks * nb + z) * sC + (long)row * ldc + col] = v;
        } else if (MODE == 4) {
          ((half_t*)Cv)[coff + (long)(col >> 6) * ((long)M * 64) + (long)row * 64 + (col & 63)]
              = (half_t)v;
        } else {
          if (OUTF16) ((half_t*)Cv)[coff + (long)row * ldc + col] = (half_t)v;
          else        ((float*)Cv)[coff + (long)row * ldc + col] = v;
        }
      }
}

// ---------------------------------------------------------------------------
// Fused attention v5: q head-blocked [b][h][4096][64] -> staged through the
// Ks LDS region (time-multiplexed) to registers; then kE/vFt staged; flash-
// chunked swapped QK^T -> online softmax -> PV. All LDS reads swizzled.
// ---------------------------------------------------------------------------
__global__ __launch_bounds__(512, 2)
void attn_fused(const half_t* __restrict__ qhb, const half_t* __restrict__ kEh,
                const half_t* __restrict__ vFt, half_t* __restrict__ outp, int L)
{
  __shared__ __attribute__((aligned(16))) half_t Ks[256 * 64];  // 32KB (q, then kE)
  __shared__ __attribute__((aligned(16))) half_t Vs[64 * 256];  // 32KB
  const int tid = threadIdx.x, w = tid >> 6, lane = tid & 63;
  const int g = lane >> 4, c = lane & 15;
  const int l0 = blockIdx.x * 256, h = blockIdx.y, b = blockIdx.z;

  const half_t* keh = kEh + (long)(b * 16 + h) * 16384;          // [256][64]
  const half_t* vfh = vFt + (long)b * 262144 + (long)h * 16384;  // [64][256]
  const half_t* qpan = qhb + ((long)(b * 16 + h) * 4096 + l0) * 64;  // [256][64]
  half_t* ob = outp + ((long)b * L + l0 + w * 32) * 1024 + h * 64;

  // ---- stage q panel (32KB contiguous) into Ks region, swizzled ----
#pragma unroll
  for (int i = 0; i < 4; ++i) {
    const int row = i * 64 + (tid >> 3), slot = tid & 7;
    gload_lds16(qpan + row * 64 + ((slot ^ (row & 7)) << 3),
                (char*)Ks + i * 8192 + tid * 16);
  }
  __syncthreads();   // q visible

  // q fragments: qrow_local = w*32 + fi*16 + c, k-window = ks*32 + g*8
  f16x8 qf[2][2];
#pragma unroll
  for (int fi = 0; fi < 2; ++fi) {
    const int qrow = w * 32 + fi * 16 + c;
    const char* qp = (const char*)Ks + qrow * 128;
#pragma unroll
    for (int ks = 0; ks < 2; ++ks)
      qf[fi][ks] = *(const f16x8*)(qp + (((ks * 4 + g) ^ (qrow & 7)) << 4));
  }
  __syncthreads();   // all waves consumed q before overwrite

  // ---- stage kE into Ks, vFt into Vs (swizzled source, linear dest) ----
#pragma unroll
  for (int i = 0; i < 4; ++i) {
    const int row = i * 64 + (tid >> 3), slot = tid & 7;
    gload_lds16(keh + row * 64 + ((slot ^ (row & 7)) << 3),
                (char*)Ks + i * 8192 + tid * 16);
  }
#pragma unroll
  for (int i = 0; i < 4; ++i) {
    const int row = i * 16 + (tid >> 5), slot = tid & 31;
    gload_lds16(vfh + row * 256 + ((slot ^ (row & 7)) << 3),
                (char*)Vs + i * 8192 + tid * 16);
  }
  __syncthreads();   // staged K/V visible

  const f32x4 zero = {0.f, 0.f, 0.f, 0.f};
  f32x4 o[2][4];
#pragma unroll
  for (int fi = 0; fi < 2; ++fi)
#pragma unroll
    for (int fd = 0; fd < 4; ++fd) o[fi][fd] = zero;
  float mrun[2] = {-3.0e38f, -3.0e38f};
  float lrun[2] = {0.f, 0.f};

  for (int ch = 0; ch < 4; ++ch) {
    // --- QK^T chunk from LDS: S^T = kE · q^T, keys = ch*64 + fj*16 + g*4 + r
    f32x4 s[2][4];
#pragma unroll
    for (int fi = 0; fi < 2; ++fi)
#pragma unroll
      for (int fj = 0; fj < 4; ++fj) s[fi][fj] = zero;
#pragma unroll
    for (int fj = 0; fj < 4; ++fj) {
      const int krow = ch * 64 + fj * 16 + c;
      const char* kb = (const char*)Ks + krow * 128;
      f16x8 k0 = *(const f16x8*)(kb + ((g ^ (c & 7)) << 4));
      f16x8 k1 = *(const f16x8*)(kb + (((4 + g) ^ (c & 7)) << 4));
#pragma unroll
      for (int fi = 0; fi < 2; ++fi) {
        s[fi][fj] = __builtin_amdgcn_mfma_f32_16x16x32_f16(k0, qf[fi][0], s[fi][fj], 0, 0, 0);
        s[fi][fj] = __builtin_amdgcn_mfma_f32_16x16x32_f16(k1, qf[fi][1], s[fi][fj], 0, 0, 0);
      }
    }

    // --- online softmax update (per fi; qrow = col c; reduce across g) ---
    f16x4 p[2][4];
#pragma unroll
    for (int fi = 0; fi < 2; ++fi) {
      float cm = -3.0e38f;
#pragma unroll
      for (int fj = 0; fj < 4; ++fj)
#pragma unroll
        for (int r = 0; r < 4; ++r) cm = fmaxf(cm, s[fi][fj][r]);
      cm = fmaxf(cm, __shfl_xor(cm, 16));
      cm = fmaxf(cm, __shfl_xor(cm, 32));
      const float mnew = fmaxf(mrun[fi], cm);
      const float sc = __expf(mrun[fi] - mnew);
      float csum = 0.f;
#pragma unroll
      for (int fj = 0; fj < 4; ++fj) {
        f16x4 fr;
#pragma unroll
        for (int r = 0; r < 4; ++r) {
          float e = __expf(s[fi][fj][r] - mnew);
          fr[r] = (half_t)e; csum += e;
        }
        p[fi][fj] = fr;
      }
      csum += __shfl_xor(csum, 16);
      csum += __shfl_xor(csum, 32);
      lrun[fi] = lrun[fi] * sc + csum;
      mrun[fi] = mnew;
#pragma unroll
      for (int fd = 0; fd < 4; ++fd)
#pragma unroll
        for (int r = 0; r < 4; ++r) o[fi][fd][r] *= sc;
    }

    // --- PV chunk from LDS: OUT^T += vFt · P^T (K=16 per mfma) ---
#pragma unroll
    for (int kc = 0; kc < 4; ++kc) {
      const int s16 = ch * 8 + kc * 2 + (g >> 1);
      f16x4 va[4];
#pragma unroll
      for (int fd = 0; fd < 4; ++fd) {
        const int drow = fd * 16 + c;
        va[fd] = *(const f16x4*)((const char*)Vs + drow * 512 +
                                 ((s16 ^ (c & 7)) << 4) + (g & 1) * 8);
      }
#pragma unroll
      for (int fi = 0; fi < 2; ++fi)
#pragma unroll
        for (int fd = 0; fd < 4; ++fd)
          o[fi][fd] = __builtin_amdgcn_mfma_f32_16x16x16f16(va[fd], p[fi][kc], o[fi][fd], 0, 0, 0);
    }
  }

  // store OUT^T * 1/l: row = d = fd*16 + g*4 + r (contiguous -> 8B), col = qrow
#pragma unroll
  for (int fi = 0; fi < 2; ++fi) {
    const float inv = 1.0f / lrun[fi];
#pragma unroll
    for (int fd = 0; fd < 4; ++fd) {
      f16x4 st;
#pragma unroll
      for (int r = 0; r < 4; ++r) st[r] = (half_t)(o[fi][fd][r] * inv);
      *(f16x4*)(ob + (long)(fi * 16 + c) * 1024 + fd * 16 + g * 4) = st;
    }
  }
}

// ---------------------------------------------------------------------------
// helpers
// ---------------------------------------------------------------------------
__global__ void reduce4_f16(const float* __restrict__ in, half_t* __restrict__ out) {
  long i = ((long)blockIdx.x * 256 + threadIdx.x) * 4;
  float4v a = *(const float4v*)(in + i);
#pragma unroll
  for (int ks = 1; ks < 4; ++ks) {
    float4v t = *(const float4v*)(in + (long)ks * 2097152 + i);
    a.x += t.x; a.y += t.y; a.z += t.z; a.w += t.w;
  }
  f16x4 o;
  o[0] = (half_t)a.x; o[1] = (half_t)a.y; o[2] = (half_t)a.z; o[3] = (half_t)a.w;
  *(f16x4*)(out + i) = o;
}

// x [4][4096][1024] f32 -> xhf fp16 (same layout) AND xT [4][1024][4096] fp16
__global__ void xpass(const float* __restrict__ x, half_t* __restrict__ xhf,
                      half_t* __restrict__ xT) {
  __shared__ float t[32][33];
  const int b = blockIdx.z, d0 = blockIdx.x * 32, l0 = blockIdx.y * 32;
  const int tx = threadIdx.x, ty = threadIdx.y;
  const float* ip = x + ((long)b * 4096 + l0) * 1024 + d0;
  half_t* oh = xhf + ((long)b * 4096 + l0) * 1024 + d0;
#pragma unroll
  for (int j = 0; j < 4; ++j) {
    float v = ip[(long)(ty + 8 * j) * 1024 + tx];
    t[ty + 8 * j][tx] = v;
    oh[(long)(ty + 8 * j) * 1024 + tx] = (half_t)v;
  }
  __syncthreads();
  half_t* ot = xT + ((long)b * 1024 + d0) * 4096 + l0;
#pragma unroll
  for (int j = 0; j < 4; ++j)
    ot[(long)(ty + 8 * j) * 4096 + tx] = (half_t)t[tx][ty + 8 * j];
}

// merged E/F pass: z selects E or F. [4096][256] f32 -> ^T fp16 + colsum
__global__ void efpass(const float* __restrict__ E, const float* __restrict__ F,
                       half_t* __restrict__ outT, float* __restrict__ ssum) {
  __shared__ float t[32][33];
  __shared__ float ps[8][32];
  const int zz = blockIdx.z;
  const float* in = zz ? F : E;
  half_t* oT = outT + (long)zz * 1048576;
  float* sm = ssum + zz * 256;
  const int k0 = blockIdx.x * 32, l0 = blockIdx.y * 32;
  const int tx = threadIdx.x, ty = threadIdx.y;
  float p = 0.f;
#pragma unroll
  for (int j = 0; j < 4; ++j) {
    float v = in[(long)(l0 + ty + 8 * j) * 256 + k0 + tx];
    t[ty + 8 * j][tx] = v; p += v;
  }
  ps[ty][tx] = p;
  __syncthreads();
  if (ty == 0) {
    float a = 0.f;
#pragma unroll
    for (int r = 0; r < 8; ++r) a += ps[r][tx];
    atomicAdd(&sm[k0 + tx], a);
  }
#pragma unroll
  for (int j = 0; j < 4; ++j)
    oT[(long)(k0 + ty + 8 * j) * 4096 + l0 + tx] = (half_t)t[tx][ty + 8 * j];
}

// merged weight transpose: z selects Wq/Wk/Wv/Wo (all 1024x1024)
__global__ void transposeW(const float* __restrict__ W0, const float* __restrict__ W1,
                           const float* __restrict__ W2, const float* __restrict__ W3,
                           half_t* __restrict__ out0, half_t* __restrict__ out1,
                           half_t* __restrict__ out2, half_t* __restrict__ out3) {
  __shared__ float t[32][33];
  const int zz = blockIdx.z;
  const float* in = (zz == 0) ? W0 : (zz == 1) ? W1 : (zz == 2) ? W2 : W3;
  half_t* out = (zz == 0) ? out0 : (zz == 1) ? out1 : (zz == 2) ? out2 : out3;
  const int cx = blockIdx.x * 32 + threadIdx.x;
  const int r0 = blockIdx.y * 32;
#pragma unroll
  for (int j = 0; j < 4; ++j)
    t[threadIdx.y + 8 * j][threadIdx.x] = in[(long)(r0 + threadIdx.y + 8 * j) * 1024 + cx];
  __syncthreads();
  const int rx = r0 + threadIdx.x;
  const int cy = blockIdx.x * 32 + threadIdx.y;
#pragma unroll
  for (int j = 0; j < 4; ++j)
    out[(long)(cy + 8 * j) * 1024 + rx] = (half_t)t[threadIdx.x][threadIdx.y + 8 * j];
}

// ---------------------------------------------------------------------------
extern "C" void kernel_launch(void* const* d_in, const int* in_sizes, int n_in,
                              void* d_out, int out_size, void* d_ws, size_t ws_size,
                              hipStream_t stream)
{
  const float* x  = (const float*)d_in[0];
  const float* Wq = (const float*)d_in[1];
  const float* bq = (const float*)d_in[2];
  const float* Wk = (const float*)d_in[3];
  const float* bk = (const float*)d_in[4];
  const float* Wv = (const float*)d_in[5];
  const float* bv = (const float*)d_in[6];
  const float* E  = (const float*)d_in[7];
  const float* F  = (const float*)d_in[8];
  const float* Wo = (const float*)d_in[9];
  const float* bo = (const float*)d_in[10];
  float* out = (float*)d_out;

  char* ws = (char*)d_ws;
  half_t* xhf  = (half_t*)(ws);                 // 33.5MB; later reused as out_pre
  half_t* xT   = (half_t*)(ws + 33554432);      // 33.5MB (dead after xEF gemm)
  half_t* qhf  = (half_t*)(ws + 67108864);      // 33.5MB, head-blocked [b][h][l][d]
  half_t* Wqt  = (half_t*)(ws + 100663296);
  half_t* Wkt  = Wqt + 1048576;
  half_t* Wvt  = Wkt + 1048576;
  half_t* Wot  = Wvt + 1048576;
  half_t* EFt  = (half_t*)(ws + 109051904);     // [512][4096]: E^T on top of F^T
  half_t* xEF  = (half_t*)(ws + 113246208);     // per b: [512][1024] = [xE; xF]
  half_t* kEb  = (half_t*)(ws + 117440512);     // per b: [16][256][64] head-blocked
  half_t* vFtb = (half_t*)(ws + 119537664);     // per b: [16][64][256]
  float*  sEF  = (float*)(ws + 121634816);      // sE[256], sF[256]
  half_t* outp = xhf;                           // out_pre overlays x_f16
  float*  xEFf = (float*)d_out;                 // 33.5MB split-K partials in d_out

  hipMemsetAsync(sEF, 0, 2048, stream);
  dim3 tb(32, 8);
  xpass<<<dim3(32, 128, 4), tb, 0, stream>>>(x, xhf, xT);
  efpass<<<dim3(8, 128, 2), tb, 0, stream>>>(E, F, EFt, sEF);
  transposeW<<<dim3(32, 32, 4), tb, 0, stream>>>(Wq, Wk, Wv, Wo, Wqt, Wkt, Wvt, Wot);

  // xEF partials: [E^T; F^T] @ x_b  (M=512, N=1024, K=4096) split-K=4, plain f32
  gemm_bt<128,128,64,64,0,3,4><<<dim3(4, 8, 16), 256, 0, stream>>>(
      EFt, xT, (void*)xEFf, nullptr, nullptr, 512, 1024, 4096, 4096, 4096, 1024, 1.f,
      0, 4194304, 524288);
  reduce4_f16<<<2048, 256, 0, stream>>>(xEFf, xEF);

  // q = (x@Wq + bq) * hd^-0.5 -> head-blocked fp16 [b][16][4096][64]
  gemm_big<2><<<dim3(64, 4), 512, 0, stream>>>(xhf, Wqt, qhf, bq, 0.125f);
  // kE[b] = xE_b @ Wk + sE*bk -> head-blocked [b][16][256][64]  (64-tile, 256 blocks)
  gemm_bt<64,64,32,32,1,4,1><<<dim3(4, 16, 4), 256, 0, stream>>>(
      xEF, Wkt, kEb, bk, sEF, 256, 1024, 1024, 1024, 1024, 1024, 1.f,
      524288, 0, 262144);
  // vFt[b] = Wv^T @ xF_b^T + bv*sF  (M=1024, N=256, K=1024)  (64-tile, 256 blocks)
  gemm_bt<64,64,32,32,1,2,1><<<dim3(16, 4, 4), 256, 0, stream>>>(
      Wvt, xEF + 262144, vFtb, sEF + 256, bv, 1024, 256, 1024, 1024, 1024, 256, 1.f,
      0, 524288, 262144);
  // fused qk^T -> softmax -> PV   (writes out_pre fp16 [b][l][h*64+d])
  attn_fused<<<dim3(16, 16, 4), 512, 0, stream>>>(qhf, kEb, vFtb, outp, 4096);
  // out = out_pre @ Wo + bo  (fp32, 8-phase big-GEMM)
  gemm_big<0><<<dim3(64, 4), 512, 0, stream>>>(outp, Wot, (void*)out, bo, 1.0f);
  (void)in_sizes; (void)n_in; (void)out_size; (void)ws_size;
}

// Round 13
// 216.388 us; speedup vs baseline: 1.1578x; 1.0466x over previous
//
#include <hip/hip_runtime.h>

typedef _Float16 half_t;
typedef __attribute__((ext_vector_type(8))) _Float16 f16x8;   // 8 fp16 = 4 VGPRs
typedef __attribute__((ext_vector_type(4))) _Float16 f16x4;
typedef __attribute__((ext_vector_type(4))) float f32x4;
typedef __attribute__((ext_vector_type(4))) float float4v;

__device__ __forceinline__ void gload_lds16(const void* g, void* l) {
  __builtin_amdgcn_global_load_lds(
      (const __attribute__((address_space(1))) void*)g,
      (__attribute__((address_space(3))) void*)l, 16, 0, 0);
}

// ---------------------------------------------------------------------------
// Big-GEMM (8-phase): C[16384][1024] = A * B, Bt = B^T [1024][1024].
// OUTMODE 0: f32 standard ; OUTMODE 2: f16 head-blocked [b][h][l][d]
// ---------------------------------------------------------------------------
template<int OUTMODE>
__global__ __launch_bounds__(512, 2)
void gemm_big(const half_t* __restrict__ A, const half_t* __restrict__ Bt,
              void* __restrict__ Cv, const float* __restrict__ bias, float alpha)
{
  __shared__ __attribute__((aligned(16))) char lds[131072];
  const int tid = threadIdx.x, w = tid >> 6, lane = tid & 63;
  const int wr = w >> 2, wc = w & 3;          // wave grid 2M x 4N
  const int g = lane >> 4, cc = lane & 15;
  const int m0 = blockIdx.x * 256, n0 = blockIdx.y * 256;

  const int srow2 = tid >> 2, sslot = tid & 3;
  const int swslot = sslot ^ ((srow2 >> 1) & 3);     // inverse swizzle on source
  const int swr = (g ^ ((cc >> 1) & 3)) << 4;        // swizzled read slot

  const f32x4 zero = {0.f, 0.f, 0.f, 0.f};
  f32x4 acc[8][4];
#pragma unroll
  for (int i = 0; i < 8; ++i)
#pragma unroll
    for (int j = 0; j < 4; ++j) acc[i][j] = zero;

  auto STAGE_HALF = [&](int ktile, int hh, char* sb) {
    const int kk = hh >> 1, isB = hh & 1;
    const half_t* src = isB ? Bt : A;
    const int base_row = isB ? n0 : m0;
    const long rowoff = (long)(base_row + srow2) * 1024 + ktile * 64 + kk * 32 + swslot * 8;
    char* d = sb + isB * 32768 + kk * 16384;
    gload_lds16(src + rowoff,          d + tid * 16);
    gload_lds16(src + rowoff + 131072, d + 8192 + tid * 16);
  };

  {
    char* b0 = lds;
    STAGE_HALF(0, 0, b0); STAGE_HALF(0, 1, b0);
    STAGE_HALF(0, 2, b0); STAGE_HALF(0, 3, b0);
  }
  asm volatile("s_waitcnt vmcnt(4)" ::: "memory");
  __builtin_amdgcn_s_barrier();

#pragma unroll 1
  for (int n = 0; n < 16; ++n) {
    const char* rb = lds + ((n & 1) << 16);
    char* sb = lds + (((n + 1) & 1) << 16);
    f16x8 bf[4];
#pragma unroll
    for (int ph = 0; ph < 4; ++ph) {
      const int kk = ph >> 1, fh = ph & 1;
      f16x8 af[4];
      const char* Ah = rb + kk * 16384;
#pragma unroll
      for (int mf = 0; mf < 4; ++mf)
        af[mf] = *(const f16x8*)(Ah + (wr * 128 + fh * 64 + mf * 16 + cc) * 64 + swr);
      if (fh == 0) {
        const char* Bh = rb + 32768 + kk * 16384;
#pragma unroll
        for (int nf = 0; nf < 4; ++nf)
          bf[nf] = *(const f16x8*)(Bh + (wc * 64 + nf * 16 + cc) * 64 + swr);
      }
      if (n < 15) STAGE_HALF(n + 1, ph, sb);
      __builtin_amdgcn_sched_barrier(0);
      __builtin_amdgcn_s_barrier();
      asm volatile("s_waitcnt lgkmcnt(0)" ::: "memory");
      __builtin_amdgcn_sched_barrier(0);
      __builtin_amdgcn_s_setprio(1);
#pragma unroll
      for (int mf = 0; mf < 4; ++mf)
#pragma unroll
        for (int nf = 0; nf < 4; ++nf)
          acc[fh * 4 + mf][nf] =
              __builtin_amdgcn_mfma_f32_16x16x32_f16(af[mf], bf[nf], acc[fh * 4 + mf][nf], 0, 0, 0);
      __builtin_amdgcn_s_setprio(0);
      __builtin_amdgcn_sched_barrier(0);
      if (ph == 1) {
        if (n < 15) { asm volatile("s_waitcnt vmcnt(4)" ::: "memory"); }
        else        { asm volatile("s_waitcnt vmcnt(0)" ::: "memory"); }
      } else if (ph == 3) {
        if (n < 15) { asm volatile("s_waitcnt vmcnt(4)" ::: "memory"); }
      }
      __builtin_amdgcn_s_barrier();
    }
  }

#pragma unroll
  for (int mf = 0; mf < 8; ++mf)
#pragma unroll
    for (int nf = 0; nf < 4; ++nf)
#pragma unroll
      for (int r = 0; r < 4; ++r) {
        const int row = m0 + wr * 128 + mf * 16 + g * 4 + r;  // D: row=(l>>4)*4+reg
        const int col = n0 + wc * 64 + nf * 16 + cc;          //    col=l&15
        float v = (acc[mf][nf][r] + bias[col]) * alpha;
        if (OUTMODE == 0) {
          ((float*)Cv)[(long)row * 1024 + col] = v;
        } else {
          const int bb = row >> 12, l = row & 4095, h = col >> 6, d = col & 63;
          ((half_t*)Cv)[(((long)(bb * 16 + h) * 4096 + l) << 6) + d] = (half_t)v;
        }
      }
}

// ---------------------------------------------------------------------------
// Split-K GEMM for xEF: partials, plain f32 stores to slice ks (MODE3 only).
// ---------------------------------------------------------------------------
template<int SK>
__global__ __launch_bounds__(256, 2)
void gemm_xef(const half_t* __restrict__ A, const half_t* __restrict__ Bt,
              float* __restrict__ Cv, int lda, int ldb, long sB, long sC)
{
  __shared__ __attribute__((aligned(16))) half_t As[128 * 32];
  __shared__ __attribute__((aligned(16))) half_t Bs[128 * 32];

  const int tid = threadIdx.x, w = tid >> 6, lane = tid & 63;
  const int wr = w >> 1, wc = w & 1;
  const int z = blockIdx.z / SK, ks = blockIdx.z % SK;
  const half_t* Ab = A;
  const half_t* Bb = Bt + (long)z * sB;
  const int m0 = blockIdx.x * 128, n0 = blockIdx.y * 128;
  const int g = lane >> 4, cc = lane & 15;
  const int srow = lane >> 2, scol = (lane & 3) * 8;

  const f32x4 zero = {0.f, 0.f, 0.f, 0.f};
  f32x4 acc[4][4];
#pragma unroll
  for (int i = 0; i < 4; ++i)
#pragma unroll
    for (int j = 0; j < 4; ++j) acc[i][j] = zero;

  const int kchunk = 4096 / SK;
  for (int kt = ks * kchunk; kt < (ks + 1) * kchunk; kt += 32) {
#pragma unroll
    for (int j = 0; j < 2; ++j) {
      const int bi = w * 2 + j;
      gload_lds16(Ab + (long)(m0 + bi * 16 + srow) * lda + kt + scol, &As[bi * 512]);
      gload_lds16(Bb + (long)(n0 + bi * 16 + srow) * ldb + kt + scol, &Bs[bi * 512]);
    }
    __syncthreads();

    f16x8 af[4], bf[4];
#pragma unroll
    for (int i = 0; i < 4; ++i)
      af[i] = *(const f16x8*)&As[(wr * 64 + i * 16 + cc) * 32 + g * 8];
#pragma unroll
    for (int j = 0; j < 4; ++j)
      bf[j] = *(const f16x8*)&Bs[(wc * 64 + j * 16 + cc) * 32 + g * 8];
#pragma unroll
    for (int i = 0; i < 4; ++i)
#pragma unroll
      for (int j = 0; j < 4; ++j)
        acc[i][j] = __builtin_amdgcn_mfma_f32_16x16x32_f16(af[i], bf[j], acc[i][j], 0, 0, 0);
    __syncthreads();
  }

  const int nb = gridDim.z / SK;
#pragma unroll
  for (int i = 0; i < 4; ++i)
#pragma unroll
    for (int j = 0; j < 4; ++j)
#pragma unroll
      for (int r = 0; r < 4; ++r) {
        const int row = m0 + wr * 64 + i * 16 + g * 4 + r;
        const int col = n0 + wc * 64 + j * 16 + cc;
        Cv[((long)ks * nb + z) * sC + (long)row * 1024 + col] = acc[i][j][r];
      }
}

// ---------------------------------------------------------------------------
// Merged kE + vF GEMM (64x64 tiles, K=1024, 512 blocks).
// role 0 (bid<256): kE[b] = xE_b @ Wk + sE*bk -> head-blocked [b][16][256][64]
// role 1: vFt[b] = Wv^T @ xF_b^T + bv*sF -> [b][16][64][256]
// ---------------------------------------------------------------------------
__global__ __launch_bounds__(256, 2)
void gemm_kevf(const half_t* __restrict__ xEF, const half_t* __restrict__ Wkt,
               const half_t* __restrict__ Wvt, half_t* __restrict__ kEb,
               half_t* __restrict__ vFtb, const float* __restrict__ bk,
               const float* __restrict__ bv, const float* __restrict__ sEF)
{
  __shared__ __attribute__((aligned(16))) half_t As[64 * 32];
  __shared__ __attribute__((aligned(16))) half_t Bs[64 * 32];
  const int tid = threadIdx.x, w = tid >> 6, lane = tid & 63;
  const int wr = w >> 1, wc = w & 1;
  const int g = lane >> 4, cc = lane & 15;
  const int srow = lane >> 2, scol = (lane & 3) * 8;

  const int bid = blockIdx.x;
  const int role = bid >> 8, lb = bid & 255;
  const half_t *Ap, *Bp;
  int m0, n0, z;
  if (role == 0) {
    m0 = (lb & 3) * 64; n0 = ((lb >> 2) & 15) * 64; z = lb >> 6;
    Ap = xEF + (long)z * 524288;  Bp = Wkt;
  } else {
    m0 = (lb & 15) * 64; n0 = ((lb >> 4) & 3) * 64; z = lb >> 6;
    Ap = Wvt;  Bp = xEF + (long)z * 524288 + 262144;
  }

  const f32x4 zero = {0.f, 0.f, 0.f, 0.f};
  f32x4 acc[2][2];
#pragma unroll
  for (int i = 0; i < 2; ++i)
#pragma unroll
    for (int j = 0; j < 2; ++j) acc[i][j] = zero;

  for (int kt = 0; kt < 1024; kt += 32) {
    gload_lds16(Ap + (long)(m0 + w * 16 + srow) * 1024 + kt + scol, &As[w * 512]);
    gload_lds16(Bp + (long)(n0 + w * 16 + srow) * 1024 + kt + scol, &Bs[w * 512]);
    __syncthreads();
    f16x8 af[2], bf[2];
#pragma unroll
    for (int i = 0; i < 2; ++i)
      af[i] = *(const f16x8*)&As[(wr * 32 + i * 16 + cc) * 32 + g * 8];
#pragma unroll
    for (int j = 0; j < 2; ++j)
      bf[j] = *(const f16x8*)&Bs[(wc * 32 + j * 16 + cc) * 32 + g * 8];
#pragma unroll
    for (int i = 0; i < 2; ++i)
#pragma unroll
      for (int j = 0; j < 2; ++j)
        acc[i][j] = __builtin_amdgcn_mfma_f32_16x16x32_f16(af[i], bf[j], acc[i][j], 0, 0, 0);
    __syncthreads();
  }

#pragma unroll
  for (int i = 0; i < 2; ++i)
#pragma unroll
    for (int j = 0; j < 2; ++j)
#pragma unroll
      for (int r = 0; r < 4; ++r) {
        const int row = m0 + wr * 32 + i * 16 + g * 4 + r;
        const int col = n0 + wc * 32 + j * 16 + cc;
        float v = acc[i][j][r];
        if (role == 0) {
          v += sEF[row] * bk[col];
          kEb[(long)z * 262144 + (long)(col >> 6) * 16384 + (long)row * 64 + (col & 63)]
              = (half_t)v;
        } else {
          v += bv[row] * sEF[256 + col];
          vFtb[(long)z * 262144 + (long)row * 256 + col] = (half_t)v;
        }
      }
}

// ---------------------------------------------------------------------------
// Fused attention v6: q + vFt staged concurrently; kE staged after q consumed.
// Flash-chunked swapped QK^T -> online softmax (T13 defer-max) -> PV.
// ---------------------------------------------------------------------------
__global__ __launch_bounds__(512, 2)
void attn_fused(const half_t* __restrict__ qhb, const half_t* __restrict__ kEh,
                const half_t* __restrict__ vFt, half_t* __restrict__ outp, int L)
{
  __shared__ __attribute__((aligned(16))) half_t Ks[256 * 64];  // 32KB (q, then kE)
  __shared__ __attribute__((aligned(16))) half_t Vs[64 * 256];  // 32KB
  const int tid = threadIdx.x, w = tid >> 6, lane = tid & 63;
  const int g = lane >> 4, c = lane & 15;
  const int l0 = blockIdx.x * 256, h = blockIdx.y, b = blockIdx.z;

  const half_t* keh = kEh + (long)(b * 16 + h) * 16384;          // [256][64]
  const half_t* vfh = vFt + (long)b * 262144 + (long)h * 16384;  // [64][256]
  const half_t* qpan = qhb + ((long)(b * 16 + h) * 4096 + l0) * 64;  // [256][64]
  half_t* ob = outp + ((long)b * L + l0 + w * 32) * 1024 + h * 64;

  // ---- stage q panel into Ks AND vFt into Vs concurrently (swizzled) ----
#pragma unroll
  for (int i = 0; i < 4; ++i) {
    const int row = i * 64 + (tid >> 3), slot = tid & 7;
    gload_lds16(qpan + row * 64 + ((slot ^ (row & 7)) << 3),
                (char*)Ks + i * 8192 + tid * 16);
  }
#pragma unroll
  for (int i = 0; i < 4; ++i) {
    const int row = i * 16 + (tid >> 5), slot = tid & 31;
    gload_lds16(vfh + row * 256 + ((slot ^ (row & 7)) << 3),
                (char*)Vs + i * 8192 + tid * 16);
  }
  __syncthreads();   // q + vF visible

  // q fragments: qrow_local = w*32 + fi*16 + c, k-window = ks*32 + g*8
  f16x8 qf[2][2];
#pragma unroll
  for (int fi = 0; fi < 2; ++fi) {
    const int qrow = w * 32 + fi * 16 + c;
    const char* qp = (const char*)Ks + qrow * 128;
#pragma unroll
    for (int ks = 0; ks < 2; ++ks)
      qf[fi][ks] = *(const f16x8*)(qp + (((ks * 4 + g) ^ (qrow & 7)) << 4));
  }
  __syncthreads();   // all waves consumed q before overwrite

  // ---- stage kE into Ks ----
#pragma unroll
  for (int i = 0; i < 4; ++i) {
    const int row = i * 64 + (tid >> 3), slot = tid & 7;
    gload_lds16(keh + row * 64 + ((slot ^ (row & 7)) << 3),
                (char*)Ks + i * 8192 + tid * 16);
  }
  __syncthreads();   // kE visible

  const f32x4 zero = {0.f, 0.f, 0.f, 0.f};
  f32x4 o[2][4];
#pragma unroll
  for (int fi = 0; fi < 2; ++fi)
#pragma unroll
    for (int fd = 0; fd < 4; ++fd) o[fi][fd] = zero;
  float mrun[2] = {-3.0e38f, -3.0e38f};
  float lrun[2] = {0.f, 0.f};

  for (int ch = 0; ch < 4; ++ch) {
    // --- QK^T chunk from LDS: S^T = kE · q^T, keys = ch*64 + fj*16 + g*4 + r
    f32x4 s[2][4];
#pragma unroll
    for (int fi = 0; fi < 2; ++fi)
#pragma unroll
      for (int fj = 0; fj < 4; ++fj) s[fi][fj] = zero;
#pragma unroll
    for (int fj = 0; fj < 4; ++fj) {
      const int krow = ch * 64 + fj * 16 + c;
      const char* kb = (const char*)Ks + krow * 128;
      f16x8 k0 = *(const f16x8*)(kb + ((g ^ (c & 7)) << 4));
      f16x8 k1 = *(const f16x8*)(kb + (((4 + g) ^ (c & 7)) << 4));
#pragma unroll
      for (int fi = 0; fi < 2; ++fi) {
        s[fi][fj] = __builtin_amdgcn_mfma_f32_16x16x32_f16(k0, qf[fi][0], s[fi][fj], 0, 0, 0);
        s[fi][fj] = __builtin_amdgcn_mfma_f32_16x16x32_f16(k1, qf[fi][1], s[fi][fj], 0, 0, 0);
      }
    }

    // --- online softmax update with T13 defer-max ---
    f16x4 p[2][4];
#pragma unroll
    for (int fi = 0; fi < 2; ++fi) {
      float cm = -3.0e38f;
#pragma unroll
      for (int fj = 0; fj < 4; ++fj)
#pragma unroll
        for (int r = 0; r < 4; ++r) cm = fmaxf(cm, s[fi][fj][r]);
      cm = fmaxf(cm, __shfl_xor(cm, 16));
      cm = fmaxf(cm, __shfl_xor(cm, 32));
      const float mref = mrun[fi];
      const bool keep = __all(cm - mref <= 8.0f);   // wave-uniform; false on ch 0
      const float mnew = keep ? mref : fmaxf(mref, cm);
      float csum = 0.f;
#pragma unroll
      for (int fj = 0; fj < 4; ++fj) {
        f16x4 fr;
#pragma unroll
        for (int r = 0; r < 4; ++r) {
          float e = __expf(s[fi][fj][r] - mnew);   // bounded by e^8 when deferred
          fr[r] = (half_t)e; csum += e;
        }
        p[fi][fj] = fr;
      }
      csum += __shfl_xor(csum, 16);
      csum += __shfl_xor(csum, 32);
      if (keep) {
        lrun[fi] += csum;
      } else {
        const float sc = __expf(mref - mnew);   // 0 on first chunk
        lrun[fi] = lrun[fi] * sc + csum;
        mrun[fi] = mnew;
#pragma unroll
        for (int fd = 0; fd < 4; ++fd)
#pragma unroll
          for (int r = 0; r < 4; ++r) o[fi][fd][r] *= sc;
      }
    }

    // --- PV chunk from LDS: OUT^T += vFt · P^T (K=16 per mfma) ---
#pragma unroll
    for (int kc = 0; kc < 4; ++kc) {
      const int s16 = ch * 8 + kc * 2 + (g >> 1);
      f16x4 va[4];
#pragma unroll
      for (int fd = 0; fd < 4; ++fd) {
        const int drow = fd * 16 + c;
        va[fd] = *(const f16x4*)((const char*)Vs + drow * 512 +
                                 ((s16 ^ (c & 7)) << 4) + (g & 1) * 8);
      }
#pragma unroll
      for (int fi = 0; fi < 2; ++fi)
#pragma unroll
        for (int fd = 0; fd < 4; ++fd)
          o[fi][fd] = __builtin_amdgcn_mfma_f32_16x16x16f16(va[fd], p[fi][kc], o[fi][fd], 0, 0, 0);
    }
  }

  // store OUT^T * 1/l: row = d = fd*16 + g*4 + r (contiguous -> 8B), col = qrow
#pragma unroll
  for (int fi = 0; fi < 2; ++fi) {
    const float inv = 1.0f / lrun[fi];
#pragma unroll
    for (int fd = 0; fd < 4; ++fd) {
      f16x4 st;
#pragma unroll
      for (int r = 0; r < 4; ++r) st[r] = (half_t)(o[fi][fd][r] * inv);
      *(f16x4*)(ob + (long)(fi * 16 + c) * 1024 + fd * 16 + g * 4) = st;
    }
  }
}

// ---------------------------------------------------------------------------
// Merged pre-pass: xpass (16384 blocks) | efpass (2048) | transposeW (4096).
// All roles use (32,8) threads and a 32x33 LDS tile; branch is block-uniform.
// ---------------------------------------------------------------------------
__global__ __launch_bounds__(256, 4)
void prepass(const float* __restrict__ x, half_t* __restrict__ xhf,
             half_t* __restrict__ xT,
             const float* __restrict__ E, const float* __restrict__ F,
             half_t* __restrict__ EFt, float* __restrict__ sEF,
             const float* __restrict__ Wq, const float* __restrict__ Wk,
             const float* __restrict__ Wv, const float* __restrict__ Wo,
             half_t* __restrict__ Wqt, half_t* __restrict__ Wkt,
             half_t* __restrict__ Wvt, half_t* __restrict__ Wot)
{
  __shared__ float t[32][33];
  __shared__ float ps[8][32];
  const int tx = threadIdx.x, ty = threadIdx.y;
  const int id = blockIdx.x;

  if (id < 16384) {        // ---- xpass ----
    const int bx = id & 31, by = (id >> 5) & 127, bz = id >> 12;
    const int d0 = bx * 32, l0 = by * 32;
    const float* ip = x + ((long)bz * 4096 + l0) * 1024 + d0;
    half_t* oh = xhf + ((long)bz * 4096 + l0) * 1024 + d0;
#pragma unroll
    for (int j = 0; j < 4; ++j) {
      float v = ip[(long)(ty + 8 * j) * 1024 + tx];
      t[ty + 8 * j][tx] = v;
      oh[(long)(ty + 8 * j) * 1024 + tx] = (half_t)v;
    }
    __syncthreads();
    half_t* ot = xT + ((long)bz * 1024 + d0) * 4096 + l0;
#pragma unroll
    for (int j = 0; j < 4; ++j)
      ot[(long)(ty + 8 * j) * 4096 + tx] = (half_t)t[tx][ty + 8 * j];
  } else if (id < 18432) { // ---- efpass ----
    const int id2 = id - 16384;
    const int bx = id2 & 7, by = (id2 >> 3) & 127, zz = id2 >> 10;
    const float* in = zz ? F : E;
    half_t* oT = EFt + (long)zz * 1048576;
    float* sm = sEF + zz * 256;
    const int k0 = bx * 32, l0 = by * 32;
    float p = 0.f;
#pragma unroll
    for (int j = 0; j < 4; ++j) {
      float v = in[(long)(l0 + ty + 8 * j) * 256 + k0 + tx];
      t[ty + 8 * j][tx] = v; p += v;
    }
    ps[ty][tx] = p;
    __syncthreads();
    if (ty == 0) {
      float a = 0.f;
#pragma unroll
      for (int r = 0; r < 8; ++r) a += ps[r][tx];
      atomicAdd(&sm[k0 + tx], a);
    }
#pragma unroll
    for (int j = 0; j < 4; ++j)
      oT[(long)(k0 + ty + 8 * j) * 4096 + l0 + tx] = (half_t)t[tx][ty + 8 * j];
  } else {                 // ---- transposeW ----
    const int id3 = id - 18432;
    const int bx = id3 & 31, by = (id3 >> 5) & 31, zz = id3 >> 10;
    const float* in = (zz == 0) ? Wq : (zz == 1) ? Wk : (zz == 2) ? Wv : Wo;
    half_t* out = (zz == 0) ? Wqt : (zz == 1) ? Wkt : (zz == 2) ? Wvt : Wot;
    const int cx = bx * 32 + tx, r0 = by * 32;
#pragma unroll
    for (int j = 0; j < 4; ++j)
      t[ty + 8 * j][tx] = in[(long)(r0 + ty + 8 * j) * 1024 + cx];
    __syncthreads();
    const int rx = r0 + tx, cy = bx * 32 + ty;
#pragma unroll
    for (int j = 0; j < 4; ++j)
      out[(long)(cy + 8 * j) * 1024 + rx] = (half_t)t[tx][ty + 8 * j];
  }
}

// sum 4 split-K f32 partial slices -> fp16
__global__ void reduce4_f16(const float* __restrict__ in, half_t* __restrict__ out) {
  long i = ((long)blockIdx.x * 256 + threadIdx.x) * 4;
  float4v a = *(const float4v*)(in + i);
#pragma unroll
  for (int ks = 1; ks < 4; ++ks) {
    float4v t = *(const float4v*)(in + (long)ks * 2097152 + i);
    a.x += t.x; a.y += t.y; a.z += t.z; a.w += t.w;
  }
  f16x4 o;
  o[0] = (half_t)a.x; o[1] = (half_t)a.y; o[2] = (half_t)a.z; o[3] = (half_t)a.w;
  *(f16x4*)(out + i) = o;
}

// ---------------------------------------------------------------------------
extern "C" void kernel_launch(void* const* d_in, const int* in_sizes, int n_in,
                              void* d_out, int out_size, void* d_ws, size_t ws_size,
                              hipStream_t stream)
{
  const float* x  = (const float*)d_in[0];
  const float* Wq = (const float*)d_in[1];
  const float* bq = (const float*)d_in[2];
  const float* Wk = (const float*)d_in[3];
  const float* bk = (const float*)d_in[4];
  const float* Wv = (const float*)d_in[5];
  const float* bv = (const float*)d_in[6];
  const float* E  = (const float*)d_in[7];
  const float* F  = (const float*)d_in[8];
  const float* Wo = (const float*)d_in[9];
  const float* bo = (const float*)d_in[10];
  float* out = (float*)d_out;

  char* ws = (char*)d_ws;
  half_t* xhf  = (half_t*)(ws);                 // 33.5MB; later reused as out_pre
  half_t* xT   = (half_t*)(ws + 33554432);      // 33.5MB (dead after xEF gemm)
  half_t* qhf  = (half_t*)(ws + 67108864);      // 33.5MB, head-blocked [b][h][l][d]
  half_t* Wqt  = (half_t*)(ws + 100663296);
  half_t* Wkt  = Wqt + 1048576;
  half_t* Wvt  = Wkt + 1048576;
  half_t* Wot  = Wvt + 1048576;
  half_t* EFt  = (half_t*)(ws + 109051904);     // [512][4096]: E^T on top of F^T
  half_t* xEF  = (half_t*)(ws + 113246208);     // per b: [512][1024] = [xE; xF]
  half_t* kEb  = (half_t*)(ws + 117440512);     // per b: [16][256][64] head-blocked
  half_t* vFtb = (half_t*)(ws + 119537664);     // per b: [16][64][256]
  float*  sEF  = (float*)(ws + 121634816);      // sE[256], sF[256]
  half_t* outp = xhf;                           // out_pre overlays x_f16
  float*  xEFf = (float*)d_out;                 // 33.5MB split-K partials in d_out

  hipMemsetAsync(sEF, 0, 2048, stream);
  // merged pre-pass (xpass | efpass | transposeW)
  prepass<<<dim3(22528), dim3(32, 8), 0, stream>>>(
      x, xhf, xT, E, F, EFt, sEF, Wq, Wk, Wv, Wo, Wqt, Wkt, Wvt, Wot);

  // xEF partials: [E^T; F^T] @ x_b  (M=512, N=1024, K=4096) split-K=4, plain f32
  gemm_xef<4><<<dim3(4, 8, 16), 256, 0, stream>>>(
      EFt, xT, xEFf, 4096, 4096, 4194304, 524288);
  reduce4_f16<<<2048, 256, 0, stream>>>(xEFf, xEF);

  // q = (x@Wq + bq) * hd^-0.5 -> head-blocked fp16 [b][16][4096][64]
  gemm_big<2><<<dim3(64, 4), 512, 0, stream>>>(xhf, Wqt, qhf, bq, 0.125f);
  // merged kE + vF
  gemm_kevf<<<dim3(512), 256, 0, stream>>>(xEF, Wkt, Wvt, kEb, vFtb, bk, bv, sEF);
  // fused qk^T -> softmax -> PV   (writes out_pre fp16 [b][l][h*64+d])
  attn_fused<<<dim3(16, 16, 4), 512, 0, stream>>>(qhf, kEb, vFtb, outp, 4096);
  // out = out_pre @ Wo + bo  (fp32, 8-phase big-GEMM)
  gemm_big<0><<<dim3(64, 4), 512, 0, stream>>>(outp, Wot, (void*)out, bo, 1.0f);
  (void)bq; (void)in_sizes; (void)n_in; (void)out_size; (void)ws_size;
}

// Round 14
// 213.774 us; speedup vs baseline: 1.1719x; 1.0122x over previous
//
#include <hip/hip_runtime.h>

typedef _Float16 half_t;
typedef __attribute__((ext_vector_type(8))) _Float16 f16x8;   // 8 fp16 = 4 VGPRs
typedef __attribute__((ext_vector_type(4))) _Float16 f16x4;
typedef __attribute__((ext_vector_type(4))) float f32x4;
typedef __attribute__((ext_vector_type(4))) float float4v;

__device__ __forceinline__ void gload_lds16(const void* g, void* l) {
  __builtin_amdgcn_global_load_lds(
      (const __attribute__((address_space(1))) void*)g,
      (__attribute__((address_space(3))) void*)l, 16, 0, 0);
}

// ---------------------------------------------------------------------------
// Big-GEMM (8-phase): C[16384][1024] = A * B, Bt = B^T [1024][1024].
// OUTMODE 0: f32 standard ; OUTMODE 2: f16 head-blocked [b][h][l][d]
// ---------------------------------------------------------------------------
template<int OUTMODE>
__global__ __launch_bounds__(512, 2)
void gemm_big(const half_t* __restrict__ A, const half_t* __restrict__ Bt,
              void* __restrict__ Cv, const float* __restrict__ bias, float alpha)
{
  __shared__ __attribute__((aligned(16))) char lds[131072];
  const int tid = threadIdx.x, w = tid >> 6, lane = tid & 63;
  const int wr = w >> 2, wc = w & 3;          // wave grid 2M x 4N
  const int g = lane >> 4, cc = lane & 15;
  const int m0 = blockIdx.x * 256, n0 = blockIdx.y * 256;

  const int srow2 = tid >> 2, sslot = tid & 3;
  const int swslot = sslot ^ ((srow2 >> 1) & 3);     // inverse swizzle on source
  const int swr = (g ^ ((cc >> 1) & 3)) << 4;        // swizzled read slot

  const f32x4 zero = {0.f, 0.f, 0.f, 0.f};
  f32x4 acc[8][4];
#pragma unroll
  for (int i = 0; i < 8; ++i)
#pragma unroll
    for (int j = 0; j < 4; ++j) acc[i][j] = zero;

  auto STAGE_HALF = [&](int ktile, int hh, char* sb) {
    const int kk = hh >> 1, isB = hh & 1;
    const half_t* src = isB ? Bt : A;
    const int base_row = isB ? n0 : m0;
    const long rowoff = (long)(base_row + srow2) * 1024 + ktile * 64 + kk * 32 + swslot * 8;
    char* d = sb + isB * 32768 + kk * 16384;
    gload_lds16(src + rowoff,          d + tid * 16);
    gload_lds16(src + rowoff + 131072, d + 8192 + tid * 16);
  };

  {
    char* b0 = lds;
    STAGE_HALF(0, 0, b0); STAGE_HALF(0, 1, b0);
    STAGE_HALF(0, 2, b0); STAGE_HALF(0, 3, b0);
  }
  asm volatile("s_waitcnt vmcnt(4)" ::: "memory");
  __builtin_amdgcn_s_barrier();

#pragma unroll 1
  for (int n = 0; n < 16; ++n) {
    const char* rb = lds + ((n & 1) << 16);
    char* sb = lds + (((n + 1) & 1) << 16);
    f16x8 bf[4];
#pragma unroll
    for (int ph = 0; ph < 4; ++ph) {
      const int kk = ph >> 1, fh = ph & 1;
      f16x8 af[4];
      const char* Ah = rb + kk * 16384;
#pragma unroll
      for (int mf = 0; mf < 4; ++mf)
        af[mf] = *(const f16x8*)(Ah + (wr * 128 + fh * 64 + mf * 16 + cc) * 64 + swr);
      if (fh == 0) {
        const char* Bh = rb + 32768 + kk * 16384;
#pragma unroll
        for (int nf = 0; nf < 4; ++nf)
          bf[nf] = *(const f16x8*)(Bh + (wc * 64 + nf * 16 + cc) * 64 + swr);
      }
      if (n < 15) STAGE_HALF(n + 1, ph, sb);
      __builtin_amdgcn_sched_barrier(0);
      __builtin_amdgcn_s_barrier();
      asm volatile("s_waitcnt lgkmcnt(0)" ::: "memory");
      __builtin_amdgcn_sched_barrier(0);
      __builtin_amdgcn_s_setprio(1);
#pragma unroll
      for (int mf = 0; mf < 4; ++mf)
#pragma unroll
        for (int nf = 0; nf < 4; ++nf)
          acc[fh * 4 + mf][nf] =
              __builtin_amdgcn_mfma_f32_16x16x32_f16(af[mf], bf[nf], acc[fh * 4 + mf][nf], 0, 0, 0);
      __builtin_amdgcn_s_setprio(0);
      __builtin_amdgcn_sched_barrier(0);
      if (ph == 1) {
        if (n < 15) { asm volatile("s_waitcnt vmcnt(4)" ::: "memory"); }
        else        { asm volatile("s_waitcnt vmcnt(0)" ::: "memory"); }
      } else if (ph == 3) {
        if (n < 15) { asm volatile("s_waitcnt vmcnt(4)" ::: "memory"); }
      }
      __builtin_amdgcn_s_barrier();
    }
  }

#pragma unroll
  for (int mf = 0; mf < 8; ++mf)
#pragma unroll
    for (int nf = 0; nf < 4; ++nf)
#pragma unroll
      for (int r = 0; r < 4; ++r) {
        const int row = m0 + wr * 128 + mf * 16 + g * 4 + r;  // D: row=(l>>4)*4+reg
        const int col = n0 + wc * 64 + nf * 16 + cc;          //    col=l&15
        float v = (acc[mf][nf][r] + bias[col]) * alpha;
        if (OUTMODE == 0) {
          ((float*)Cv)[(long)row * 1024 + col] = v;
        } else {
          const int bb = row >> 12, l = row & 4095, h = col >> 6, d = col & 63;
          ((half_t*)Cv)[(((long)(bb * 16 + h) * 4096 + l) << 6) + d] = (half_t)v;
        }
      }
}

// ---------------------------------------------------------------------------
// Split-K GEMM for xEF: partials, plain f32 stores to slice ks.
// ---------------------------------------------------------------------------
template<int SK>
__global__ __launch_bounds__(256, 2)
void gemm_xef(const half_t* __restrict__ A, const half_t* __restrict__ Bt,
              float* __restrict__ Cv, int lda, int ldb, long sB, long sC)
{
  __shared__ __attribute__((aligned(16))) half_t As[128 * 32];
  __shared__ __attribute__((aligned(16))) half_t Bs[128 * 32];

  const int tid = threadIdx.x, w = tid >> 6, lane = tid & 63;
  const int wr = w >> 1, wc = w & 1;
  const int z = blockIdx.z / SK, ks = blockIdx.z % SK;
  const half_t* Ab = A;
  const half_t* Bb = Bt + (long)z * sB;
  const int m0 = blockIdx.x * 128, n0 = blockIdx.y * 128;
  const int g = lane >> 4, cc = lane & 15;
  const int srow = lane >> 2, scol = (lane & 3) * 8;

  const f32x4 zero = {0.f, 0.f, 0.f, 0.f};
  f32x4 acc[4][4];
#pragma unroll
  for (int i = 0; i < 4; ++i)
#pragma unroll
    for (int j = 0; j < 4; ++j) acc[i][j] = zero;

  const int kchunk = 4096 / SK;
  for (int kt = ks * kchunk; kt < (ks + 1) * kchunk; kt += 32) {
#pragma unroll
    for (int j = 0; j < 2; ++j) {
      const int bi = w * 2 + j;
      gload_lds16(Ab + (long)(m0 + bi * 16 + srow) * lda + kt + scol, &As[bi * 512]);
      gload_lds16(Bb + (long)(n0 + bi * 16 + srow) * ldb + kt + scol, &Bs[bi * 512]);
    }
    __syncthreads();

    f16x8 af[4], bf[4];
#pragma unroll
    for (int i = 0; i < 4; ++i)
      af[i] = *(const f16x8*)&As[(wr * 64 + i * 16 + cc) * 32 + g * 8];
#pragma unroll
    for (int j = 0; j < 4; ++j)
      bf[j] = *(const f16x8*)&Bs[(wc * 64 + j * 16 + cc) * 32 + g * 8];
#pragma unroll
    for (int i = 0; i < 4; ++i)
#pragma unroll
      for (int j = 0; j < 4; ++j)
        acc[i][j] = __builtin_amdgcn_mfma_f32_16x16x32_f16(af[i], bf[j], acc[i][j], 0, 0, 0);
    __syncthreads();
  }

  const int nb = gridDim.z / SK;
#pragma unroll
  for (int i = 0; i < 4; ++i)
#pragma unroll
    for (int j = 0; j < 4; ++j)
#pragma unroll
      for (int r = 0; r < 4; ++r) {
        const int row = m0 + wr * 64 + i * 16 + g * 4 + r;
        const int col = n0 + wc * 64 + j * 16 + cc;
        Cv[((long)ks * nb + z) * sC + (long)row * 1024 + col] = acc[i][j][r];
      }
}

// ---------------------------------------------------------------------------
// Merged kE + vF GEMM (64x64 tiles, K=1024, 512 blocks).
// ---------------------------------------------------------------------------
__global__ __launch_bounds__(256, 2)
void gemm_kevf(const half_t* __restrict__ xEF, const half_t* __restrict__ Wkt,
               const half_t* __restrict__ Wvt, half_t* __restrict__ kEb,
               half_t* __restrict__ vFtb, const float* __restrict__ bk,
               const float* __restrict__ bv, const float* __restrict__ sEF)
{
  __shared__ __attribute__((aligned(16))) half_t As[64 * 32];
  __shared__ __attribute__((aligned(16))) half_t Bs[64 * 32];
  const int tid = threadIdx.x, w = tid >> 6, lane = tid & 63;
  const int wr = w >> 1, wc = w & 1;
  const int g = lane >> 4, cc = lane & 15;
  const int srow = lane >> 2, scol = (lane & 3) * 8;

  const int bid = blockIdx.x;
  const int role = bid >> 8, lb = bid & 255;
  const half_t *Ap, *Bp;
  int m0, n0, z;
  if (role == 0) {
    m0 = (lb & 3) * 64; n0 = ((lb >> 2) & 15) * 64; z = lb >> 6;
    Ap = xEF + (long)z * 524288;  Bp = Wkt;
  } else {
    m0 = (lb & 15) * 64; n0 = ((lb >> 4) & 3) * 64; z = lb >> 6;
    Ap = Wvt;  Bp = xEF + (long)z * 524288 + 262144;
  }

  const f32x4 zero = {0.f, 0.f, 0.f, 0.f};
  f32x4 acc[2][2];
#pragma unroll
  for (int i = 0; i < 2; ++i)
#pragma unroll
    for (int j = 0; j < 2; ++j) acc[i][j] = zero;

  for (int kt = 0; kt < 1024; kt += 32) {
    gload_lds16(Ap + (long)(m0 + w * 16 + srow) * 1024 + kt + scol, &As[w * 512]);
    gload_lds16(Bp + (long)(n0 + w * 16 + srow) * 1024 + kt + scol, &Bs[w * 512]);
    __syncthreads();
    f16x8 af[2], bf[2];
#pragma unroll
    for (int i = 0; i < 2; ++i)
      af[i] = *(const f16x8*)&As[(wr * 32 + i * 16 + cc) * 32 + g * 8];
#pragma unroll
    for (int j = 0; j < 2; ++j)
      bf[j] = *(const f16x8*)&Bs[(wc * 32 + j * 16 + cc) * 32 + g * 8];
#pragma unroll
    for (int i = 0; i < 2; ++i)
#pragma unroll
      for (int j = 0; j < 2; ++j)
        acc[i][j] = __builtin_amdgcn_mfma_f32_16x16x32_f16(af[i], bf[j], acc[i][j], 0, 0, 0);
    __syncthreads();
  }

#pragma unroll
  for (int i = 0; i < 2; ++i)
#pragma unroll
    for (int j = 0; j < 2; ++j)
#pragma unroll
      for (int r = 0; r < 4; ++r) {
        const int row = m0 + wr * 32 + i * 16 + g * 4 + r;
        const int col = n0 + wc * 32 + j * 16 + cc;
        float v = acc[i][j][r];
        if (role == 0) {
          v += sEF[row] * bk[col];
          kEb[(long)z * 262144 + (long)(col >> 6) * 16384 + (long)row * 64 + (col & 63)]
              = (half_t)v;
        } else {
          v += bv[row] * sEF[256 + col];
          vFtb[(long)z * 262144 + (long)row * 256 + col] = (half_t)v;
        }
      }
}

// ---------------------------------------------------------------------------
// Fused attention v7: kE+vF staged concurrently (one barrier total); q read
// straight to registers from head-blocked layout (L1-friendly 128B rows).
// Flash-chunked swapped QK^T -> online softmax (T13 defer-max) -> PV.
// ---------------------------------------------------------------------------
__global__ __launch_bounds__(512, 2)
void attn_fused(const half_t* __restrict__ qhb, const half_t* __restrict__ kEh,
                const half_t* __restrict__ vFt, half_t* __restrict__ outp, int L)
{
  __shared__ __attribute__((aligned(16))) half_t Ks[256 * 64];  // 32KB
  __shared__ __attribute__((aligned(16))) half_t Vs[64 * 256];  // 32KB
  const int tid = threadIdx.x, w = tid >> 6, lane = tid & 63;
  const int g = lane >> 4, c = lane & 15;
  const int l0 = blockIdx.x * 256, h = blockIdx.y, b = blockIdx.z;

  const half_t* keh = kEh + (long)(b * 16 + h) * 16384;          // [256][64]
  const half_t* vfh = vFt + (long)b * 262144 + (long)h * 16384;  // [64][256]
  const half_t* qpan = qhb + ((long)(b * 16 + h) * 4096 + l0) * 64;  // [256][64]
  half_t* ob = outp + ((long)b * L + l0 + w * 32) * 1024 + h * 64;

  // ---- stage kE -> Ks and vF -> Vs concurrently (swizzled source) ----
#pragma unroll
  for (int i = 0; i < 4; ++i) {
    const int row = i * 64 + (tid >> 3), slot = tid & 7;
    gload_lds16(keh + row * 64 + ((slot ^ (row & 7)) << 3),
                (char*)Ks + i * 8192 + tid * 16);
  }
#pragma unroll
  for (int i = 0; i < 4; ++i) {
    const int row = i * 16 + (tid >> 5), slot = tid & 31;
    gload_lds16(vfh + row * 256 + ((slot ^ (row & 7)) << 3),
                (char*)Vs + i * 8192 + tid * 16);
  }

  // ---- q direct to registers (overlaps the staging loads) ----
  f16x8 qf[2][2];
#pragma unroll
  for (int fi = 0; fi < 2; ++fi)
#pragma unroll
    for (int ks = 0; ks < 2; ++ks)
      qf[fi][ks] = *(const f16x8*)(qpan + (w * 32 + fi * 16 + c) * 64 + ks * 32 + g * 8);

  __syncthreads();   // staged kE/vF visible

  const f32x4 zero = {0.f, 0.f, 0.f, 0.f};
  f32x4 o[2][4];
#pragma unroll
  for (int fi = 0; fi < 2; ++fi)
#pragma unroll
    for (int fd = 0; fd < 4; ++fd) o[fi][fd] = zero;
  float mrun[2] = {-3.0e38f, -3.0e38f};
  float lrun[2] = {0.f, 0.f};

  for (int ch = 0; ch < 4; ++ch) {
    // --- QK^T chunk from LDS: S^T = kE · q^T, keys = ch*64 + fj*16 + g*4 + r
    f32x4 s[2][4];
#pragma unroll
    for (int fi = 0; fi < 2; ++fi)
#pragma unroll
      for (int fj = 0; fj < 4; ++fj) s[fi][fj] = zero;
#pragma unroll
    for (int fj = 0; fj < 4; ++fj) {
      const int krow = ch * 64 + fj * 16 + c;
      const char* kb = (const char*)Ks + krow * 128;
      f16x8 k0 = *(const f16x8*)(kb + ((g ^ (c & 7)) << 4));
      f16x8 k1 = *(const f16x8*)(kb + (((4 + g) ^ (c & 7)) << 4));
#pragma unroll
      for (int fi = 0; fi < 2; ++fi) {
        s[fi][fj] = __builtin_amdgcn_mfma_f32_16x16x32_f16(k0, qf[fi][0], s[fi][fj], 0, 0, 0);
        s[fi][fj] = __builtin_amdgcn_mfma_f32_16x16x32_f16(k1, qf[fi][1], s[fi][fj], 0, 0, 0);
      }
    }

    // --- online softmax update with T13 defer-max ---
    f16x4 p[2][4];
#pragma unroll
    for (int fi = 0; fi < 2; ++fi) {
      float cm = -3.0e38f;
#pragma unroll
      for (int fj = 0; fj < 4; ++fj)
#pragma unroll
        for (int r = 0; r < 4; ++r) cm = fmaxf(cm, s[fi][fj][r]);
      cm = fmaxf(cm, __shfl_xor(cm, 16));
      cm = fmaxf(cm, __shfl_xor(cm, 32));
      const float mref = mrun[fi];
      const bool keep = __all(cm - mref <= 8.0f);   // wave-uniform; false on ch 0
      const float mnew = keep ? mref : fmaxf(mref, cm);
      float csum = 0.f;
#pragma unroll
      for (int fj = 0; fj < 4; ++fj) {
        f16x4 fr;
#pragma unroll
        for (int r = 0; r < 4; ++r) {
          float e = __expf(s[fi][fj][r] - mnew);   // bounded by e^8 when deferred
          fr[r] = (half_t)e; csum += e;
        }
        p[fi][fj] = fr;
      }
      csum += __shfl_xor(csum, 16);
      csum += __shfl_xor(csum, 32);
      if (keep) {
        lrun[fi] += csum;
      } else {
        const float sc = __expf(mref - mnew);   // 0 on first chunk
        lrun[fi] = lrun[fi] * sc + csum;
        mrun[fi] = mnew;
#pragma unroll
        for (int fd = 0; fd < 4; ++fd)
#pragma unroll
          for (int r = 0; r < 4; ++r) o[fi][fd][r] *= sc;
      }
    }

    // --- PV chunk from LDS: OUT^T += vFt · P^T (K=16 per mfma) ---
#pragma unroll
    for (int kc = 0; kc < 4; ++kc) {
      const int s16 = ch * 8 + kc * 2 + (g >> 1);
      f16x4 va[4];
#pragma unroll
      for (int fd = 0; fd < 4; ++fd) {
        const int drow = fd * 16 + c;
        va[fd] = *(const f16x4*)((const char*)Vs + drow * 512 +
                                 ((s16 ^ (c & 7)) << 4) + (g & 1) * 8);
      }
#pragma unroll
      for (int fi = 0; fi < 2; ++fi)
#pragma unroll
        for (int fd = 0; fd < 4; ++fd)
          o[fi][fd] = __builtin_amdgcn_mfma_f32_16x16x16f16(va[fd], p[fi][kc], o[fi][fd], 0, 0, 0);
    }
  }

  // store OUT^T * 1/l: row = d = fd*16 + g*4 + r (contiguous -> 8B), col = qrow
#pragma unroll
  for (int fi = 0; fi < 2; ++fi) {
    const float inv = 1.0f / lrun[fi];
#pragma unroll
    for (int fd = 0; fd < 4; ++fd) {
      f16x4 st;
#pragma unroll
      for (int r = 0; r < 4; ++r) st[r] = (half_t)(o[fi][fd][r] * inv);
      *(f16x4*)(ob + (long)(fi * 16 + c) * 1024 + fd * 16 + g * 4) = st;
    }
  }
}

// ---------------------------------------------------------------------------
// Merged pre-pass, 64x64 tiles, (64,4) threads -> all fp16 writes are 128B.
// roles: xpass (4096 blocks) | efpass (512) | transposeW (1024). Total 5632.
// ---------------------------------------------------------------------------
__global__ __launch_bounds__(256, 4)
void prepass(const float* __restrict__ x, half_t* __restrict__ xhf,
             half_t* __restrict__ xT,
             const float* __restrict__ E, const float* __restrict__ F,
             half_t* __restrict__ EFt, float* __restrict__ sEF,
             const float* __restrict__ Wq, const float* __restrict__ Wk,
             const float* __restrict__ Wv, const float* __restrict__ Wo,
             half_t* __restrict__ Wqt, half_t* __restrict__ Wkt,
             half_t* __restrict__ Wvt, half_t* __restrict__ Wot)
{
  __shared__ float t[64][65];
  __shared__ float ps[4][64];
  const int tx = threadIdx.x, ty = threadIdx.y;   // (64,4)
  const int id = blockIdx.x;

  if (id < 4096) {         // ---- xpass: 16 d-tiles x 64 l-tiles x 4 b ----
    const int bx = id & 15, by = (id >> 4) & 63, bz = id >> 10;
    const int d0 = bx * 64, l0 = by * 64;
    const float* ip = x + ((long)bz * 4096 + l0) * 1024 + d0;
    half_t* oh = xhf + ((long)bz * 4096 + l0) * 1024 + d0;
#pragma unroll
    for (int j = 0; j < 16; ++j) {
      const int row = ty + 4 * j;
      float v = ip[(long)row * 1024 + tx];
      t[row][tx] = v;
      oh[(long)row * 1024 + tx] = (half_t)v;
    }
    __syncthreads();
    half_t* ot = xT + ((long)bz * 1024 + d0) * 4096 + l0;
#pragma unroll
    for (int j = 0; j < 16; ++j) {
      const int drow = ty + 4 * j;
      ot[(long)drow * 4096 + tx] = (half_t)t[tx][drow];
    }
  } else if (id < 4608) {  // ---- efpass: 4 k-tiles x 64 l-tiles x 2 ----
    const int id2 = id - 4096;
    const int bx = id2 & 3, by = (id2 >> 2) & 63, zz = id2 >> 8;
    const float* in = zz ? F : E;
    half_t* oT = EFt + (long)zz * 1048576;
    float* sm = sEF + zz * 256;
    const int k0 = bx * 64, l0 = by * 64;
    float p = 0.f;
#pragma unroll
    for (int j = 0; j < 16; ++j) {
      const int row = ty + 4 * j;
      float v = in[(long)(l0 + row) * 256 + k0 + tx];
      t[row][tx] = v; p += v;
    }
    ps[ty][tx] = p;
    __syncthreads();
    if (ty == 0) {
      float a = ps[0][tx] + ps[1][tx] + ps[2][tx] + ps[3][tx];
      atomicAdd(&sm[k0 + tx], a);
    }
#pragma unroll
    for (int j = 0; j < 16; ++j) {
      const int krow = ty + 4 * j;
      oT[(long)(k0 + krow) * 4096 + l0 + tx] = (half_t)t[tx][krow];
    }
  } else {                 // ---- transposeW: 16 x 16 x 4 ----
    const int id3 = id - 4608;
    const int bx = id3 & 15, by = (id3 >> 4) & 15, zz = id3 >> 8;
    const float* in = (zz == 0) ? Wq : (zz == 1) ? Wk : (zz == 2) ? Wv : Wo;
    half_t* out = (zz == 0) ? Wqt : (zz == 1) ? Wkt : (zz == 2) ? Wvt : Wot;
    const int c0 = bx * 64, r0 = by * 64;
#pragma unroll
    for (int j = 0; j < 16; ++j) {
      const int row = ty + 4 * j;
      t[row][tx] = in[(long)(r0 + row) * 1024 + c0 + tx];
    }
    __syncthreads();
#pragma unroll
    for (int j = 0; j < 16; ++j) {
      const int crow = ty + 4 * j;
      out[(long)(c0 + crow) * 1024 + r0 + tx] = (half_t)t[tx][crow];
    }
  }
}

// sum 4 split-K f32 partial slices -> fp16
__global__ void reduce4_f16(const float* __restrict__ in, half_t* __restrict__ out) {
  long i = ((long)blockIdx.x * 256 + threadIdx.x) * 4;
  float4v a = *(const float4v*)(in + i);
#pragma unroll
  for (int ks = 1; ks < 4; ++ks) {
    float4v t = *(const float4v*)(in + (long)ks * 2097152 + i);
    a.x += t.x; a.y += t.y; a.z += t.z; a.w += t.w;
  }
  f16x4 o;
  o[0] = (half_t)a.x; o[1] = (half_t)a.y; o[2] = (half_t)a.z; o[3] = (half_t)a.w;
  *(f16x4*)(out + i) = o;
}

// ---------------------------------------------------------------------------
extern "C" void kernel_launch(void* const* d_in, const int* in_sizes, int n_in,
                              void* d_out, int out_size, void* d_ws, size_t ws_size,
                              hipStream_t stream)
{
  const float* x  = (const float*)d_in[0];
  const float* Wq = (const float*)d_in[1];
  const float* bq = (const float*)d_in[2];
  const float* Wk = (const float*)d_in[3];
  const float* bk = (const float*)d_in[4];
  const float* Wv = (const float*)d_in[5];
  const float* bv = (const float*)d_in[6];
  const float* E  = (const float*)d_in[7];
  const float* F  = (const float*)d_in[8];
  const float* Wo = (const float*)d_in[9];
  const float* bo = (const float*)d_in[10];
  float* out = (float*)d_out;

  char* ws = (char*)d_ws;
  half_t* xhf  = (half_t*)(ws);                 // 33.5MB; later reused as out_pre
  half_t* xT   = (half_t*)(ws + 33554432);      // 33.5MB (dead after xEF gemm)
  half_t* qhf  = (half_t*)(ws + 67108864);      // 33.5MB, head-blocked [b][h][l][d]
  half_t* Wqt  = (half_t*)(ws + 100663296);
  half_t* Wkt  = Wqt + 1048576;
  half_t* Wvt  = Wkt + 1048576;
  half_t* Wot  = Wvt + 1048576;
  half_t* EFt  = (half_t*)(ws + 109051904);     // [512][4096]: E^T on top of F^T
  half_t* xEF  = (half_t*)(ws + 113246208);     // per b: [512][1024] = [xE; xF]
  half_t* kEb  = (half_t*)(ws + 117440512);     // per b: [16][256][64] head-blocked
  half_t* vFtb = (half_t*)(ws + 119537664);     // per b: [16][64][256]
  float*  sEF  = (float*)(ws + 121634816);      // sE[256], sF[256]
  half_t* outp = xhf;                           // out_pre overlays x_f16
  float*  xEFf = (float*)d_out;                 // 33.5MB split-K partials in d_out

  hipMemsetAsync(sEF, 0, 2048, stream);
  // merged pre-pass (xpass | efpass | transposeW), 128B-write tiles
  prepass<<<dim3(5632), dim3(64, 4), 0, stream>>>(
      x, xhf, xT, E, F, EFt, sEF, Wq, Wk, Wv, Wo, Wqt, Wkt, Wvt, Wot);

  // xEF partials: [E^T; F^T] @ x_b  (M=512, N=1024, K=4096) split-K=4, plain f32
  gemm_xef<4><<<dim3(4, 8, 16), 256, 0, stream>>>(
      EFt, xT, xEFf, 4096, 4096, 4194304, 524288);
  reduce4_f16<<<2048, 256, 0, stream>>>(xEFf, xEF);

  // q = (x@Wq + bq) * hd^-0.5 -> head-blocked fp16 [b][16][4096][64]
  gemm_big<2><<<dim3(64, 4), 512, 0, stream>>>(xhf, Wqt, qhf, bq, 0.125f);
  // merged kE + vF
  gemm_kevf<<<dim3(512), 256, 0, stream>>>(xEF, Wkt, Wvt, kEb, vFtb, bk, bv, sEF);
  // fused qk^T -> softmax -> PV   (writes out_pre fp16 [b][l][h*64+d])
  attn_fused<<<dim3(16, 16, 4), 512, 0, stream>>>(qhf, kEb, vFtb, outp, 4096);
  // out = out_pre @ Wo + bo  (fp32, 8-phase big-GEMM)
  gemm_big<0><<<dim3(64, 4), 512, 0, stream>>>(outp, Wot, (void*)out, bo, 1.0f);
  (void)bq; (void)in_sizes; (void)n_in; (void)out_size; (void)ws_size;
}